// Round 16
// baseline (1042.792 us; speedup 1.0000x reference)
//
#include <hip/hip_runtime.h>
#include <math.h>

#define TPB 256

typedef __attribute__((ext_vector_type(8))) short short8v;
typedef __attribute__((ext_vector_type(4))) short short4v;
typedef __attribute__((ext_vector_type(4))) float f32x4;

// ---------------------------------------------------------------------------
// bf16 helpers
// ---------------------------------------------------------------------------
__device__ __forceinline__ float b2f(unsigned short u) {
  union { unsigned i; float f; } x; x.i = ((unsigned)u) << 16; return x.f;
}
__device__ __forceinline__ unsigned short f2b(float f) {
  union { float f; unsigned i; } x; x.f = f;
  unsigned r = (x.i + 0x7fffu + ((x.i >> 16) & 1u)) >> 16;
  return (unsigned short)r;
}

__device__ __forceinline__ float4 ld4(const float* p) { return *(const float4*)p; }

__device__ __forceinline__ void fma4(float s, const float4 w, float4& a) {
  a.x = fmaf(s, w.x, a.x); a.y = fmaf(s, w.y, a.y);
  a.z = fmaf(s, w.z, a.z); a.w = fmaf(s, w.w, a.w);
}

template<int Co>
__device__ __forceinline__ float4 bn_relu4(float4 a, const float* __restrict__ bn, int cg) {
  const float4 g = ld4(bn + cg * 4);
  const float4 b = ld4(bn + Co + cg * 4);
  const float4 m = ld4(bn + 2 * Co + cg * 4);
  const float4 v = ld4(bn + 3 * Co + cg * 4);
  float4 r;
  r.x = fmaxf((a.x - m.x) * (g.x * rsqrtf(v.x + 1e-5f)) + b.x, 0.f);
  r.y = fmaxf((a.y - m.y) * (g.y * rsqrtf(v.y + 1e-5f)) + b.y, 0.f);
  r.z = fmaxf((a.z - m.z) * (g.z * rsqrtf(v.z + 1e-5f)) + b.z, 0.f);
  r.w = fmaxf((a.w - m.w) * (g.w * rsqrtf(v.w + 1e-5f)) + b.w, 0.f);
  return r;
}

// ---------------------------------------------------------------------------
// mask pyramid
// ---------------------------------------------------------------------------
template<int LW, int LH, int D>
__global__ void __launch_bounds__(TPB) k_maskpool(const float* __restrict__ mf,
                                                  float* __restrict__ mc) {
  constexpr int W = 1 << LW, H = 1 << LH;
  constexpr int total = D * H * W;
  const int v = blockIdx.x * TPB + threadIdx.x;
  if (v >= total) return;
  const int w = v & (W - 1), h = (v >> LW) & (H - 1), d = v >> (LW + LH);
  float mp = 0.f;
  #pragma unroll
  for (int dz = 0; dz < 2; ++dz)
    #pragma unroll
    for (int hz = 0; hz < 2; ++hz)
      #pragma unroll
      for (int wz = 0; wz < 2; ++wz)
        mp = fmaxf(mp, mf[((((2*d+dz) << (LH+1)) + (2*h+hz)) << (LW+1)) + (2*w+wz)]);
  mc[v] = mp;
}

// ---------------------------------------------------------------------------
// deterministic ordered compaction: count -> scan -> fill
// ---------------------------------------------------------------------------
__global__ void __launch_bounds__(TPB) k_count(const float* __restrict__ m, int total,
                                               int* __restrict__ bcount) {
  const int v = blockIdx.x * TPB + threadIdx.x;
  const bool act = (v < total) && (m[v] != 0.f);
  const unsigned long long b = __ballot(act);
  __shared__ int wc[TPB / 64];
  const int wid = threadIdx.x >> 6;
  if ((threadIdx.x & 63) == 0) wc[wid] = __popcll(b);
  __syncthreads();
  if (threadIdx.x == 0) bcount[blockIdx.x] = wc[0] + wc[1] + wc[2] + wc[3];
}

__global__ void __launch_bounds__(1024) k_scan(const int* __restrict__ bc, int nb,
                                               int* __restrict__ boff, int* __restrict__ total) {
  __shared__ int part[1024];
  const int t = threadIdx.x;
  const int a0 = (2 * t     < nb) ? bc[2 * t]     : 0;
  const int a1 = (2 * t + 1 < nb) ? bc[2 * t + 1] : 0;
  part[t] = a0 + a1;
  __syncthreads();
  for (int off = 1; off < 1024; off <<= 1) {
    const int tmp = (t >= off) ? part[t - off] : 0;
    __syncthreads();
    part[t] += tmp;
    __syncthreads();
  }
  const int excl = (t == 0) ? 0 : part[t - 1];
  if (2 * t     < nb) boff[2 * t]     = excl;
  if (2 * t + 1 < nb) boff[2 * t + 1] = excl + a0;
  if (t == 1023) *total = part[1023];
}

__global__ void __launch_bounds__(TPB) k_fill(const float* __restrict__ m, int total,
                                              const int* __restrict__ boff,
                                              int* __restrict__ list) {
  const int v = blockIdx.x * TPB + threadIdx.x;
  const bool act = (v < total) && (m[v] != 0.f);
  const unsigned long long b = __ballot(act);
  const int wid = threadIdx.x >> 6, lane = threadIdx.x & 63;
  __shared__ int wc[TPB / 64];
  __shared__ int wbase[TPB / 64];
  if (lane == 0) wc[wid] = __popcll(b);
  __syncthreads();
  if (threadIdx.x == 0) {
    int s = boff[blockIdx.x];
    #pragma unroll
    for (int i = 0; i < TPB / 64; ++i) { wbase[i] = s; s += wc[i]; }
  }
  __syncthreads();
  if (act) {
    const int rank = __popcll(b & ((1ull << lane) - 1ull));
    list[wbase[wid] + rank] = v;
  }
}

// ---------------------------------------------------------------------------
// x: fp32 [NV][20] -> bf16 [NV][32]
// ---------------------------------------------------------------------------
__global__ void __launch_bounds__(TPB) k_cvtx(const float* __restrict__ x,
                                              unsigned short* __restrict__ xb, int NV) {
  const int v = blockIdx.x * TPB + threadIdx.x;
  if (v >= NV) return;
  const float* r = x + (size_t)v * 20;
  unsigned short* o = xb + (size_t)v * 32;
  #pragma unroll
  for (int c4 = 0; c4 < 5; ++c4) {
    const float4 f = ld4(r + c4 * 4);
    short4v s; s[0] = (short)f2b(f.x); s[1] = (short)f2b(f.y);
    s[2] = (short)f2b(f.z); s[3] = (short)f2b(f.w);
    *(short4v*)(o + c4 * 4) = s;
  }
  const short4v z = {0, 0, 0, 0};
  *(short4v*)(o + 20) = z; *(short4v*)(o + 24) = z; *(short4v*)(o + 28) = z;
}

// ---------------------------------------------------------------------------
// weight pack: fp32 [27][C1r+C2][Co] -> bf16 MFMA-B fragments.
// ---------------------------------------------------------------------------
template<int C1r, int C1p, int C2, int Co>
__global__ void __launch_bounds__(TPB) k_packw(const float* __restrict__ w,
                                               unsigned short* __restrict__ pw) {
  constexpr int NT = Co / 16;
  constexpr int NKC = (C1p + C2) / 32;
  constexpr int total = 27 * NT * NKC * 512;
  const int idx = blockIdx.x * TPB + threadIdx.x;
  if (idx >= total) return;
  const int j = idx & 7;
  const int l = (idx >> 3) & 63;
  int rest = idx >> 9;
  const int kc = rest % NKC; rest /= NKC;
  const int nt = rest % NT;
  const int t = rest / NT;
  const int k = kc * 32 + ((l >> 4) << 3) + j;
  const int n = nt * 16 + (l & 15);
  int ksrc;
  if (k < C1p) ksrc = (k < C1r) ? k : -1;
  else         ksrc = C1r + (k - C1p);
  const float val = (ksrc < 0) ? 0.f : w[((size_t)t * (C1r + C2) + ksrc) * Co + n];
  pw[idx] = f2b(val);
}

// ---------------------------------------------------------------------------
// activation A-pack (dst-indexed, writes its own zeros -> no memset needed):
// pka[s][d][h][wt][kc][l][8]; lane l holds voxel wt*16+(l&15)+s-1,
// channels kc*32+(l>>4)*8..+8. OOB w -> zeros.
// ---------------------------------------------------------------------------
template<int C, int LW, int LH, int D>
__global__ void __launch_bounds__(TPB) k_packa(const unsigned short* __restrict__ xb,
                                               unsigned short* __restrict__ pka) {
  constexpr int W = 1 << LW, H = 1 << LH;
  constexpr int NKC = C / 32;
  constexpr int NWT = W / 16;
  const int total = 3 * D * H * NWT * NKC * 64;
  int idx = blockIdx.x * TPB + threadIdx.x;
  if (idx >= total) return;
  const int l = idx & 63; idx >>= 6;
  const int kc = idx % NKC; idx /= NKC;
  const int wt = idx % NWT; idx /= NWT;
  const int h = idx % H; idx /= H;
  const int d = idx % D;
  const int s = idx / D;
  const int lm = l & 15, lg = l >> 4;
  const int w = wt * 16 + lm + s - 1;
  unsigned short* dst = pka +
    ((((size_t)(s * D + d) * H + h) * NWT + wt) * NKC + kc) * 512 + l * 8;
  if ((unsigned)w < (unsigned)W) {
    const unsigned short* src = xb + ((size_t)((((d << LH) + h) << LW) + w)) * C + kc * 32 + lg * 8;
    *(short4v*)dst = *(const short4v*)src;
    *(short4v*)(dst + 4) = *(const short4v*)(src + 4);
  } else {
    const short4v z = {0, 0, 0, 0};
    *(short4v*)dst = z;
    *(short4v*)(dst + 4) = z;
  }
}

// ---------------------------------------------------------------------------
// DENSE subm via MFMA with PACKED A + A-reuse across ALL NT co-tiles:
// one contiguous 1KB A-load feeds NT MFMAs. Wave = (d, h, 16-w tile).
// out = relu(bn(conv)) * mask (writes every voxel).
// ---------------------------------------------------------------------------
template<int Co, int LW, int LH, int D, int NKC1, int NKC>
__global__ void __launch_bounds__(TPB) k_subm_dp(
    const unsigned short* __restrict__ pk1, const unsigned short* __restrict__ pk2,
    const unsigned short* __restrict__ pw, const float* __restrict__ bn,
    const float* __restrict__ mask, const unsigned short* __restrict__ ztile,
    unsigned short* __restrict__ out)
{
  constexpr int NT = Co / 16;
  constexpr int H = 1 << LH, W = 1 << LW;
  constexpr int NWT = W / 16;
  const int wv = threadIdx.x >> 6, l = threadIdx.x & 63;
  const int lm = l & 15, lg = l >> 4;
  const int total = D * H * NWT;

  for (int u = blockIdx.x * 4 + wv; u < total; u += gridDim.x * 4) {
    int rest = u;
    const int wt = rest % NWT; rest /= NWT;
    const int h = rest & (H - 1);
    const int d = rest >> LH;
    f32x4 acc[NT];
    #pragma unroll
    for (int nt = 0; nt < NT; ++nt) acc[nt] = (f32x4){0.f, 0.f, 0.f, 0.f};

    for (int t = 0; t < 27; ++t) {
      const int kd = t / 9, kh = (t / 3) % 3, s = t % 3;
      const int zd = d + kd - 1, zh = h + kh - 1;
      const bool inb = ((unsigned)zd < (unsigned)D) & ((unsigned)zh < (unsigned)H);
      const size_t tile = (((size_t)(s * D + (inb ? zd : 0)) * H + (inb ? zh : 0)) * NWT + wt);
      #pragma unroll
      for (int kc = 0; kc < NKC; ++kc) {
        const unsigned short* src;
        if (kc < NKC1)
          src = inb ? pk1 + (tile * NKC1 + kc) * 512 : ztile;
        else
          src = inb ? pk2 + (tile * (NKC - NKC1) + (kc - NKC1)) * 512 : ztile;
        const short8v a = *(const short8v*)(src + l * 8);
        #pragma unroll
        for (int nt = 0; nt < NT; ++nt) {
          const short8v b = *(const short8v*)(pw + ((((size_t)t * NT + nt) * NKC + kc) << 9) + l * 8);
          acc[nt] = __builtin_amdgcn_mfma_f32_16x16x32_bf16(a, b, acc[nt], 0, 0, 0);
        }
      }
    }

    #pragma unroll
    for (int nt = 0; nt < NT; ++nt) {
      const int co = nt * 16 + lm;
      const float sc = bn[co] * rsqrtf(bn[3 * Co + co] + 1e-5f);
      const float sh = bn[Co + co] - bn[2 * Co + co] * sc;
      #pragma unroll
      for (int i = 0; i < 4; ++i) {
        const int wo = wt * 16 + lg * 4 + i;
        const int v = (((d << LH) + h) << LW) + wo;
        const float y = fmaxf(acc[nt][i] * sc + sh, 0.f) * mask[v];
        out[(size_t)v * Co + co] = f2b(y);
      }
    }
  }
}

// ---------------------------------------------------------------------------
// subm via MFMA (sparse list, full 27 taps): exact R8 body.
// ---------------------------------------------------------------------------
template<int C1p, int C2, int Co, int LW, int LH, int D>
__global__ void __launch_bounds__(TPB) k_subm_m(
    const unsigned short* __restrict__ xb1, const unsigned short* __restrict__ xb2,
    const unsigned short* __restrict__ pw, const float* __restrict__ bn,
    const int* __restrict__ list, const int* __restrict__ cnt,
    const unsigned short* __restrict__ zb, unsigned short* __restrict__ out)
{
  constexpr int NT = Co / 16;
  constexpr int NKC1 = C1p / 32;
  constexpr int NKC = (C1p + C2) / 32;
  constexpr int MH = (NT >= 4) ? 1 : 2;
  constexpr int NTPW = (NT >= 4) ? NT / 4 : 1;
  constexpr int MVB = 32 * MH;
  constexpr int H = 1 << LH, W = 1 << LW;

  const int n = *cnt;
  if (n == 0) return;
  const int nmt = (n + MVB - 1) / MVB;
  const int wv = threadIdx.x >> 6, l = threadIdx.x & 63;
  const int mhalf = (MH == 2) ? (wv >> 1) : 0;
  const int nt0   = (MH == 2) ? (wv & 1) : wv * NTPW;
  const int lm = l & 15, lg = l >> 4;

  for (int mt = blockIdx.x; mt < nmt; mt += gridDim.x) {
    const int r0 = mt * MVB + mhalf * 32;
    int wx[2], hy[2], dzz[2];
    #pragma unroll
    for (int h2 = 0; h2 < 2; ++h2) {
      const int g = min(r0 + h2 * 16 + lm, n - 1);
      const int v = list[g];
      wx[h2] = v & (W - 1); hy[h2] = (v >> LW) & (H - 1); dzz[h2] = v >> (LW + LH);
    }
    f32x4 acc[NTPW][2];
    #pragma unroll
    for (int q = 0; q < NTPW; ++q)
      #pragma unroll
      for (int h2 = 0; h2 < 2; ++h2)
        acc[q][h2] = (f32x4){0.f, 0.f, 0.f, 0.f};

    for (int t = 0; t < 27; ++t) {
      const int kd = t / 9, kh = (t / 3) % 3, kw = t % 3;
      const unsigned short* p1[2];
      const unsigned short* p2[2];
      #pragma unroll
      for (int h2 = 0; h2 < 2; ++h2) {
        const int zd0 = dzz[h2] + kd - 1, zh0 = hy[h2] + kh - 1, zw0 = wx[h2] + kw - 1;
        const bool inb = ((unsigned)zd0 < (unsigned)D) &
                         ((unsigned)zh0 < (unsigned)H) &
                         ((unsigned)zw0 < (unsigned)W);
        const int zd = min(max(zd0, 0), D - 1);
        const int zh = min(max(zh0, 0), H - 1);
        const int zw = min(max(zw0, 0), W - 1);
        const int nv = (((zd << LH) + zh) << LW) + zw;
        p1[h2] = (inb ? xb1 + (size_t)nv * C1p : zb) + lg * 8;
        if constexpr (C2 > 0) p2[h2] = (inb ? xb2 + (size_t)nv * C2 : zb) + lg * 8;
      }
      #pragma unroll
      for (int kc = 0; kc < NKC; ++kc) {
        short8v a0, a1;
        if (C2 == 0 || kc < NKC1) {
          const int coff = kc * 32;
          a0 = *(const short8v*)(p1[0] + coff);
          a1 = *(const short8v*)(p1[1] + coff);
        } else {
          const int coff = (kc - NKC1) * 32;
          a0 = *(const short8v*)(p2[0] + coff);
          a1 = *(const short8v*)(p2[1] + coff);
        }
        #pragma unroll
        for (int q = 0; q < NTPW; ++q) {
          const int nt = nt0 + q;
          const short8v b = *(const short8v*)(pw + ((((size_t)t * NT + nt) * NKC + kc) << 9) + l * 8);
          acc[q][0] = __builtin_amdgcn_mfma_f32_16x16x32_bf16(a0, b, acc[q][0], 0, 0, 0);
          acc[q][1] = __builtin_amdgcn_mfma_f32_16x16x32_bf16(a1, b, acc[q][1], 0, 0, 0);
        }
      }
    }
    #pragma unroll
    for (int q = 0; q < NTPW; ++q) {
      const int nt = nt0 + q;
      const int co = nt * 16 + lm;
      const float sc = bn[co] * rsqrtf(bn[3 * Co + co] + 1e-5f);
      const float sh = bn[Co + co] - bn[2 * Co + co] * sc;
      #pragma unroll
      for (int h2 = 0; h2 < 2; ++h2)
        #pragma unroll
        for (int i = 0; i < 4; ++i) {
          const int g = r0 + h2 * 16 + lg * 4 + i;
          if (g < n) {
            const int v = list[g];
            const float y = fmaxf(acc[q][h2][i] * sc + sh, 0.f);
            out[(size_t)v * Co + co] = f2b(y);
          }
        }
    }
  }
}

// ---------------------------------------------------------------------------
// subm via MFMA, TAP-SPLIT (deep layers): exact R8 body.
// ---------------------------------------------------------------------------
template<int C1p, int C2, int Co, int LW, int LH, int D, int NSPLIT, int CAP>
__global__ void __launch_bounds__(TPB) k_subm_mp(
    const unsigned short* __restrict__ xb1, const unsigned short* __restrict__ xb2,
    const unsigned short* __restrict__ pw,
    const int* __restrict__ list, const int* __restrict__ cnt,
    const unsigned short* __restrict__ zb, float* __restrict__ pbuf)
{
  constexpr int NT = Co / 16;
  constexpr int NKC1 = C1p / 32;
  constexpr int NKC = (C1p + C2) / 32;
  constexpr int MH = (NT >= 4) ? 1 : 2;
  constexpr int NTPW = (NT >= 4) ? NT / 4 : 1;
  constexpr int MVB = 32 * MH;
  constexpr int TPS = 27 / NSPLIT;
  constexpr int H = 1 << LH, W = 1 << LW;

  const int n = *cnt;
  if (n == 0) return;
  const int nmt = (n + MVB - 1) / MVB;
  const int s = blockIdx.y;
  const int wv = threadIdx.x >> 6, l = threadIdx.x & 63;
  const int mhalf = (MH == 2) ? (wv >> 1) : 0;
  const int nt0   = (MH == 2) ? (wv & 1) : wv * NTPW;
  const int lm = l & 15, lg = l >> 4;

  for (int mt = blockIdx.x; mt < nmt; mt += gridDim.x) {
    const int r0 = mt * MVB + mhalf * 32;
    int wx[2], hy[2], dzz[2];
    #pragma unroll
    for (int h2 = 0; h2 < 2; ++h2) {
      const int g = min(r0 + h2 * 16 + lm, n - 1);
      const int v = list[g];
      wx[h2] = v & (W - 1); hy[h2] = (v >> LW) & (H - 1); dzz[h2] = v >> (LW + LH);
    }
    f32x4 acc[NTPW][2];
    #pragma unroll
    for (int q = 0; q < NTPW; ++q)
      #pragma unroll
      for (int h2 = 0; h2 < 2; ++h2)
        acc[q][h2] = (f32x4){0.f, 0.f, 0.f, 0.f};

    for (int t = s * TPS; t < (s + 1) * TPS; ++t) {
      const int kd = t / 9, kh = (t / 3) % 3, kw = t % 3;
      const unsigned short* p1[2];
      const unsigned short* p2[2];
      #pragma unroll
      for (int h2 = 0; h2 < 2; ++h2) {
        const int zd0 = dzz[h2] + kd - 1, zh0 = hy[h2] + kh - 1, zw0 = wx[h2] + kw - 1;
        const bool inb = ((unsigned)zd0 < (unsigned)D) &
                         ((unsigned)zh0 < (unsigned)H) &
                         ((unsigned)zw0 < (unsigned)W);
        const int zd = min(max(zd0, 0), D - 1);
        const int zh = min(max(zh0, 0), H - 1);
        const int zw = min(max(zw0, 0), W - 1);
        const int nv = (((zd << LH) + zh) << LW) + zw;
        p1[h2] = (inb ? xb1 + (size_t)nv * C1p : zb) + lg * 8;
        if constexpr (C2 > 0) p2[h2] = (inb ? xb2 + (size_t)nv * C2 : zb) + lg * 8;
      }
      #pragma unroll
      for (int kc = 0; kc < NKC; ++kc) {
        short8v a0, a1;
        if (C2 == 0 || kc < NKC1) {
          const int coff = kc * 32;
          a0 = *(const short8v*)(p1[0] + coff);
          a1 = *(const short8v*)(p1[1] + coff);
        } else {
          const int coff = (kc - NKC1) * 32;
          a0 = *(const short8v*)(p2[0] + coff);
          a1 = *(const short8v*)(p2[1] + coff);
        }
        #pragma unroll
        for (int q = 0; q < NTPW; ++q) {
          const int nt = nt0 + q;
          const short8v b = *(const short8v*)(pw + ((((size_t)t * NT + nt) * NKC + kc) << 9) + l * 8);
          acc[q][0] = __builtin_amdgcn_mfma_f32_16x16x32_bf16(a0, b, acc[q][0], 0, 0, 0);
          acc[q][1] = __builtin_amdgcn_mfma_f32_16x16x32_bf16(a1, b, acc[q][1], 0, 0, 0);
        }
      }
    }
    #pragma unroll
    for (int q = 0; q < NTPW; ++q) {
      const int co = (nt0 + q) * 16 + lm;
      #pragma unroll
      for (int h2 = 0; h2 < 2; ++h2)
        #pragma unroll
        for (int i = 0; i < 4; ++i) {
          const int g = r0 + h2 * 16 + lg * 4 + i;
          if (g < n)
            pbuf[((size_t)s * CAP + g) * Co + co] = acc[q][h2][i];
        }
    }
  }
}

// sum NSPLIT fp32 partials in fixed order + BN + ReLU -> bf16 out
template<int Co, int NSPLIT, int CAP>
__global__ void __launch_bounds__(TPB) k_reduce_bnb(
    const float* __restrict__ pbuf, const float* __restrict__ bn,
    const int* __restrict__ list, const int* __restrict__ cnt,
    unsigned short* __restrict__ out)
{
  constexpr int TPV = Co / 4;
  const int n = *cnt;
  const int total = n * TPV;
  for (int i = blockIdx.x * TPB + threadIdx.x; i < total; i += gridDim.x * TPB) {
    const int a = i / TPV;
    const int cg = i % TPV;
    float4 acc = make_float4(0.f, 0.f, 0.f, 0.f);
    #pragma unroll
    for (int s = 0; s < NSPLIT; ++s) {
      const float4 p = ld4(pbuf + ((size_t)s * CAP + a) * Co + cg * 4);
      acc.x += p.x; acc.y += p.y; acc.z += p.z; acc.w += p.w;
    }
    const int v = list[a];
    const float4 r = bn_relu4<Co>(acc, bn, cg);
    short4v o; o[0] = (short)f2b(r.x); o[1] = (short)f2b(r.y);
    o[2] = (short)f2b(r.z); o[3] = (short)f2b(r.w);
    *(short4v*)(out + (size_t)v * Co + cg * 4) = o;
  }
}

// ---------------------------------------------------------------------------
// down: 2x2x2 stride-2 conv + BN + ReLU; bf16 acts, fp32 weights/math
// ---------------------------------------------------------------------------
template<int Ci, int Co, int LW, int LH, int D>
__global__ void __launch_bounds__(TPB) k_down_b(
    const unsigned short* __restrict__ x, const float* __restrict__ wgt,
    const float* __restrict__ bn, const float* __restrict__ mfine,
    const int* __restrict__ list, const int* __restrict__ cnt,
    unsigned short* __restrict__ out)
{
  constexpr int TPV = Co / 4;
  constexpr int H = 1 << LH, W = 1 << LW;
  const int n = *cnt;
  const int total = n * TPV;
  for (int i = blockIdx.x * TPB + threadIdx.x; i < total; i += gridDim.x * TPB) {
    const int a = i / TPV;
    const int cg = i % TPV;
    const int v = list[a];
    const int w = v & (W - 1), h = (v >> LW) & (H - 1), d = v >> (LW + LH);
    float4 acc0 = make_float4(0.f, 0.f, 0.f, 0.f);
    float4 acc1 = make_float4(0.f, 0.f, 0.f, 0.f);
    #pragma unroll
    for (int kd = 0; kd < 2; ++kd)
      #pragma unroll
      for (int kh = 0; kh < 2; ++kh)
        #pragma unroll
        for (int kw = 0; kw < 2; ++kw) {
          const int nv = ((((2*d+kd) << (LH+1)) + (2*h+kh)) << (LW+1)) + (2*w+kw);
          if (mfine[nv] == 0.f) continue;
          const int tap = (kd * 2 + kh) * 2 + kw;
          const float4* __restrict__ wp = (const float4*)wgt + (size_t)tap * Ci * TPV + cg;
          const unsigned short* row = x + (size_t)nv * Ci;
          #pragma unroll
          for (int c8 = 0; c8 < Ci / 8; ++c8) {
            const short8v s = *(const short8v*)(row + c8 * 8);
            fma4(b2f((unsigned short)s[0]), wp[(c8 * 8 + 0) * TPV], acc0);
            fma4(b2f((unsigned short)s[1]), wp[(c8 * 8 + 1) * TPV], acc1);
            fma4(b2f((unsigned short)s[2]), wp[(c8 * 8 + 2) * TPV], acc0);
            fma4(b2f((unsigned short)s[3]), wp[(c8 * 8 + 3) * TPV], acc1);
            fma4(b2f((unsigned short)s[4]), wp[(c8 * 8 + 4) * TPV], acc0);
            fma4(b2f((unsigned short)s[5]), wp[(c8 * 8 + 5) * TPV], acc1);
            fma4(b2f((unsigned short)s[6]), wp[(c8 * 8 + 6) * TPV], acc0);
            fma4(b2f((unsigned short)s[7]), wp[(c8 * 8 + 7) * TPV], acc1);
          }
        }
    float4 acc;
    acc.x = acc0.x + acc1.x; acc.y = acc0.y + acc1.y;
    acc.z = acc0.z + acc1.z; acc.w = acc0.w + acc1.w;
    const float4 r = bn_relu4<Co>(acc, bn, cg);
    short4v o; o[0] = (short)f2b(r.x); o[1] = (short)f2b(r.y);
    o[2] = (short)f2b(r.z); o[3] = (short)f2b(r.w);
    *(short4v*)(out + (size_t)v * Co + cg * 4) = o;
  }
}

// ---------------------------------------------------------------------------
// up: 1-tap conv_transpose; bf16 acts, fp32 weights/math
// ---------------------------------------------------------------------------
template<int Ci, int Co, int LW, int LH>
__global__ void __launch_bounds__(TPB) k_up_b(
    const unsigned short* __restrict__ x, const float* __restrict__ wgt,
    const int* __restrict__ list, const int* __restrict__ cnt,
    unsigned short* __restrict__ out)
{
  constexpr int TPV = Co / 4;
  constexpr int H = 1 << LH, W = 1 << LW;
  const int n = *cnt;
  const int total = n * TPV;
  for (int i = blockIdx.x * TPB + threadIdx.x; i < total; i += gridDim.x * TPB) {
    const int a = i / TPV;
    const int cg = i % TPV;
    const int v = list[a];
    const int w = v & (W - 1), h = (v >> LW) & (H - 1), d = v >> (LW + LH);
    const int kd = 1 - (d & 1), kh = 1 - (h & 1), kw = 1 - (w & 1);
    const int nv = ((((d >> 1) << (LH - 1)) + (h >> 1)) << (LW - 1)) + (w >> 1);
    const int tap = (kd * 2 + kh) * 2 + kw;
    const float4* __restrict__ wp = (const float4*)wgt + (size_t)tap * Ci * TPV + cg;
    const unsigned short* row = x + (size_t)nv * Ci;
    float4 acc0 = make_float4(0.f, 0.f, 0.f, 0.f);
    float4 acc1 = make_float4(0.f, 0.f, 0.f, 0.f);
    #pragma unroll
    for (int c8 = 0; c8 < Ci / 8; ++c8) {
      const short8v s = *(const short8v*)(row + c8 * 8);
      fma4(b2f((unsigned short)s[0]), wp[(c8 * 8 + 0) * TPV], acc0);
      fma4(b2f((unsigned short)s[1]), wp[(c8 * 8 + 1) * TPV], acc1);
      fma4(b2f((unsigned short)s[2]), wp[(c8 * 8 + 2) * TPV], acc0);
      fma4(b2f((unsigned short)s[3]), wp[(c8 * 8 + 3) * TPV], acc1);
      fma4(b2f((unsigned short)s[4]), wp[(c8 * 8 + 4) * TPV], acc0);
      fma4(b2f((unsigned short)s[5]), wp[(c8 * 8 + 5) * TPV], acc1);
      fma4(b2f((unsigned short)s[6]), wp[(c8 * 8 + 6) * TPV], acc0);
      fma4(b2f((unsigned short)s[7]), wp[(c8 * 8 + 7) * TPV], acc1);
    }
    short4v o;
    o[0] = (short)f2b(acc0.x + acc1.x); o[1] = (short)f2b(acc0.y + acc1.y);
    o[2] = (short)f2b(acc0.z + acc1.z); o[3] = (short)f2b(acc0.w + acc1.w);
    *(short4v*)(out + (size_t)v * Co + cg * 4) = o;
  }
}

// ---------------------------------------------------------------------------
// head: bf16 c0, fp32 weights; scatter into 5 output regions
// ---------------------------------------------------------------------------
__global__ void __launch_bounds__(TPB) k_head_b(
    const unsigned short* __restrict__ c0, const float* __restrict__ wh,
    const float* __restrict__ bh, const int* __restrict__ list,
    const int* __restrict__ cnt, float* __restrict__ out)
{
  __shared__ float sw[32 * 45];
  __shared__ float sb[45];
  for (int t = threadIdx.x; t < 32 * 45; t += TPB) sw[t] = wh[t];
  if (threadIdx.x < 45) sb[threadIdx.x] = bh[threadIdx.x];
  __syncthreads();
  const int n = *cnt;
  const int total = n * 45;
  const size_t NV = 524288;
  for (int i = blockIdx.x * TPB + threadIdx.x; i < total; i += gridDim.x * TPB) {
    const int a = i / 45;
    const int j = i % 45;
    const int v = list[a];
    const unsigned short* cp = c0 + (size_t)v * 32;
    float a0 = 0.f, a1 = 0.f;
    #pragma unroll
    for (int c8 = 0; c8 < 4; ++c8) {
      const short8v s = *(const short8v*)(cp + c8 * 8);
      a0 = fmaf(b2f((unsigned short)s[0]), sw[(c8 * 8 + 0) * 45 + j], a0);
      a1 = fmaf(b2f((unsigned short)s[1]), sw[(c8 * 8 + 1) * 45 + j], a1);
      a0 = fmaf(b2f((unsigned short)s[2]), sw[(c8 * 8 + 2) * 45 + j], a0);
      a1 = fmaf(b2f((unsigned short)s[3]), sw[(c8 * 8 + 3) * 45 + j], a1);
      a0 = fmaf(b2f((unsigned short)s[4]), sw[(c8 * 8 + 4) * 45 + j], a0);
      a1 = fmaf(b2f((unsigned short)s[5]), sw[(c8 * 8 + 5) * 45 + j], a1);
      a0 = fmaf(b2f((unsigned short)s[6]), sw[(c8 * 8 + 6) * 45 + j], a0);
      a1 = fmaf(b2f((unsigned short)s[7]), sw[(c8 * 8 + 7) * 45 + j], a1);
    }
    const float val = a0 + a1 + sb[j];
    const int k = j / 9, r = j % 9;
    if (r < 3)
      out[(size_t)v * 15 + k * 3 + r] = val;
    else if (r < 6)
      out[NV * 15 + (size_t)v * 15 + k * 3 + (r - 3)] = fminf(fmaxf(val, -5.f), 3.f);
    else if (r == 6)
      out[NV * 30 + (size_t)v * 5 + k] = val;
    else if (r == 7)
      out[NV * 35 + (size_t)v * 5 + k] = val;
    else
      out[NV * 40 + (size_t)v * 5 + k] = val;
  }
}

// ---------------------------------------------------------------------------
extern "C" void kernel_launch(void* const* d_in, const int* in_sizes, int n_in,
                              void* d_out, int out_size, void* d_ws, size_t ws_size,
                              hipStream_t stream)
{
  (void)in_sizes; (void)n_in;

  const float* x        = (const float*)d_in[0];
  const float* mask0    = (const float*)d_in[1];
  const float* w_enc0   = (const float*)d_in[2];
  const float* bn_enc0  = (const float*)d_in[3];
  const float* w_down0  = (const float*)d_in[4];
  const float* bn_down0 = (const float*)d_in[5];
  const float* w_enc1   = (const float*)d_in[6];
  const float* bn_enc1  = (const float*)d_in[7];
  const float* w_down1  = (const float*)d_in[8];
  const float* bn_down1 = (const float*)d_in[9];
  const float* w_enc2   = (const float*)d_in[10];
  const float* bn_enc2  = (const float*)d_in[11];
  const float* w_down2  = (const float*)d_in[12];
  const float* bn_down2 = (const float*)d_in[13];
  const float* w_bott   = (const float*)d_in[14];
  const float* bn_bott  = (const float*)d_in[15];
  const float* w_up2    = (const float*)d_in[16];
  const float* w_dec2   = (const float*)d_in[17];
  const float* bn_dec2  = (const float*)d_in[18];
  const float* w_up1    = (const float*)d_in[19];
  const float* w_dec1   = (const float*)d_in[20];
  const float* bn_dec1  = (const float*)d_in[21];
  const float* w_up0    = (const float*)d_in[22];
  const float* w_dec0   = (const float*)d_in[23];
  const float* bn_dec0  = (const float*)d_in[24];
  const float* w_head   = (const float*)d_in[25];
  const float* b_head   = (const float*)d_in[26];

  char* ws = (char*)d_ws;
  size_t o = 0;
  auto takeB = [&](size_t bytes) { char* p = ws + o; o += (bytes + 255) & ~(size_t)255; return p; };
  auto takeU = [&](size_t elems) { return (unsigned short*)takeB(elems * 2); };
  auto takeF = [&](size_t elems) { return (float*)takeB(elems * 4); };
  auto takeI = [&](size_t elems) { return (int*)takeB(elems * 4); };

  int*   cnt   = takeI(16);
  int*   bcnt  = takeI(2048);
  int*   boff  = takeI(2048);
  int*   list0 = takeI(524288);
  int*   list1 = takeI(65536);
  int*   list2 = takeI(8192);
  int*   list3 = takeI(1024);
  float* m1    = takeF(65536);
  float* m2    = takeF(8192);
  float* m3    = takeF(1024);
  unsigned short* zb    = takeU(256);
  unsigned short* ztile = takeU(512);
  float* pbuf = takeF(3145728);            // K-split partials (deep layers)
  // packed weights (bf16)
  unsigned short* pw_enc0 = takeU(27648);
  unsigned short* pw_enc1 = takeU(110592);
  unsigned short* pw_enc2 = takeU(442368);
  unsigned short* pw_bott = takeU(1769472);
  unsigned short* pw_dec2 = takeU(884736);
  unsigned short* pw_dec1 = takeU(221184);
  unsigned short* pw_dec0 = takeU(55296);
  // shared packed-A region: enc0 uses all 50.3M shorts (3*32768 tiles * 512);
  // later reused as enc1's pk (12.58M) and dec1's pke+pku (2 x 12.58M).
  unsigned short* pkbuf = takeU(50331648);
  unsigned short* pk0 = pkbuf;             // enc0 (3 shifts x 32768 tiles x NKC=1)
  unsigned short* pk1 = pkbuf;             // enc1 (12.58M)
  unsigned short* pke = pkbuf;             // dec1 skip  (12.58M)
  unsigned short* pku = pkbuf + 12582912;  // dec1 up    (12.58M)
  // bf16 activations
  unsigned short* xb  = takeU(16777216);
  unsigned short* e0b = takeU(16777216);
  unsigned short* d0b = takeU(4194304);    // reused as u1b
  unsigned short* e1b = takeU(4194304);
  unsigned short* d1b = takeU(1048576);    // reused as u2b
  unsigned short* e2b = takeU(1048576);
  unsigned short* d2b = takeU(262144);
  unsigned short* bbb = takeU(262144);
  unsigned short* c2b = takeU(1048576);
  unsigned short* c1b = takeU(4194304);
  unsigned short* u0b = takeU(16777216);
  unsigned short* c0b = takeU(16777216);
  if (o > ws_size) return;
  unsigned short* u1b = d0b;
  unsigned short* u2b = d1b;
  int* cnt0 = cnt, *cnt1 = cnt + 1, *cnt2 = cnt + 2, *cnt3 = cnt + 3;

  hipMemsetAsync(d_out, 0, (size_t)out_size * sizeof(float), stream);
  hipMemsetAsync(zb, 0, 256 * 2, stream);
  hipMemsetAsync(ztile, 0, 512 * 2, stream);
  hipMemsetAsync(d0b, 0, 4194304ull * 2, stream);
  hipMemsetAsync(d1b, 0, 1048576ull * 2, stream);
  hipMemsetAsync(e2b, 0, 1048576ull * 2, stream);
  hipMemsetAsync(d2b, 0, 262144ull * 2, stream);
  hipMemsetAsync(u0b, 0, 16777216ull * 2, stream);

  auto g = [](long long upper) {
    unsigned b = (unsigned)((upper + TPB - 1) / TPB);
    return dim3(b > 4096u ? 4096u : (b ? b : 1u));
  };

  // weight packs + x convert
  k_packw<20, 32, 0, 32><<<g(27648), TPB, 0, stream>>>(w_enc0, pw_enc0);
  k_packw<64, 64, 0, 64><<<g(110592), TPB, 0, stream>>>(w_enc1, pw_enc1);
  k_packw<128, 128, 0, 128><<<g(442368), TPB, 0, stream>>>(w_enc2, pw_enc2);
  k_packw<256, 256, 0, 256><<<g(1769472), TPB, 0, stream>>>(w_bott, pw_bott);
  k_packw<128, 128, 128, 128><<<g(884736), TPB, 0, stream>>>(w_dec2, pw_dec2);
  k_packw<64, 64, 64, 64><<<g(221184), TPB, 0, stream>>>(w_dec1, pw_dec1);
  k_packw<32, 32, 32, 32><<<g(55296), TPB, 0, stream>>>(w_dec0, pw_dec0);
  k_cvtx<<<dim3(524288 / TPB), TPB, 0, stream>>>(x, xb, 524288);

  // mask pyramid + ordered compaction
  k_maskpool<6, 6, 16><<<g(65536), TPB, 0, stream>>>(mask0, m1);
  k_maskpool<5, 5, 8><<<g(8192), TPB, 0, stream>>>(m1, m2);
  k_maskpool<4, 4, 4><<<g(1024), TPB, 0, stream>>>(m2, m3);
  auto compact = [&](const float* m, int total, int* list, int* cptr) {
    const int nb = total / TPB;
    k_count<<<dim3((unsigned)nb), TPB, 0, stream>>>(m, total, bcnt);
    k_scan<<<dim3(1), 1024, 0, stream>>>(bcnt, nb, boff, cptr);
    k_fill<<<dim3((unsigned)nb), TPB, 0, stream>>>(m, total, boff, list);
  };
  compact(mask0, 524288, list0, cnt0);
  compact(m1,     65536, list1, cnt1);
  compact(m2,      8192, list2, cnt2);
  compact(m3,      1024, list3, cnt3);

  // encoder
  // enc0: pack (dst-indexed, 3*32*128*8*1*64 = 6.29M threads) + dense conv
  k_packa<32, 7, 7, 32><<<dim3(24576), TPB, 0, stream>>>(xb, pk0);
  k_subm_dp<32, 7, 7, 32, 1, 1><<<dim3(8192), TPB, 0, stream>>>(pk0, nullptr, pw_enc0, bn_enc0, mask0, ztile, e0b);
  k_down_b<32, 64, 6, 6, 16><<<g(65536LL * 16), TPB, 0, stream>>>(e0b, w_down0, bn_down0, mask0, list1, cnt1, d0b);
  // enc1: pack + dense conv (A shared across all 4 co-tiles)
  k_packa<64, 6, 6, 16><<<dim3(6144), TPB, 0, stream>>>(d0b, pk1);
  k_subm_dp<64, 6, 6, 16, 2, 2><<<dim3(1024), TPB, 0, stream>>>(pk1, nullptr, pw_enc1, bn_enc1, m1, ztile, e1b);
  k_down_b<64, 128, 5, 5, 8><<<g(8192LL * 32), TPB, 0, stream>>>(e1b, w_down1, bn_down1, m1, list2, cnt2, d1b);
  // enc2: tap-split x3
  k_subm_mp<128, 0, 128, 5, 5, 8, 3, 8192><<<dim3(256, 3), TPB, 0, stream>>>(d1b, nullptr, pw_enc2, list2, cnt2, zb, pbuf);
  k_reduce_bnb<128, 3, 8192><<<g(8192LL * 32), TPB, 0, stream>>>(pbuf, bn_enc2, list2, cnt2, e2b);
  k_down_b<128, 256, 4, 4, 4><<<g(1024LL * 64), TPB, 0, stream>>>(e2b, w_down2, bn_down2, m2, list3, cnt3, d2b);
  // bottleneck: tap-split x9
  k_subm_mp<256, 0, 256, 4, 4, 4, 9, 1024><<<dim3(32, 9), TPB, 0, stream>>>(d2b, nullptr, pw_bott, list3, cnt3, zb, pbuf);
  k_reduce_bnb<256, 9, 1024><<<g(1024LL * 64), TPB, 0, stream>>>(pbuf, bn_bott, list3, cnt3, bbb);
  // decoder
  k_up_b<256, 128, 5, 5><<<g(8192LL * 32), TPB, 0, stream>>>(bbb, w_up2, list2, cnt2, u2b);
  // dec2: tap-split x3 (concat u2|e2)
  k_subm_mp<128, 128, 128, 5, 5, 8, 3, 8192><<<dim3(256, 3), TPB, 0, stream>>>(u2b, e2b, pw_dec2, list2, cnt2, zb, pbuf);
  k_reduce_bnb<128, 3, 8192><<<g(8192LL * 32), TPB, 0, stream>>>(pbuf, bn_dec2, list2, cnt2, c2b);
  k_up_b<128, 64, 6, 6><<<g(65536LL * 16), TPB, 0, stream>>>(c2b, w_up1, list1, cnt1, u1b);
  // dec1: pack u1b+e1b, dense conv (concat u1|e1, A shared across co-tiles)
  k_packa<64, 6, 6, 16><<<dim3(6144), TPB, 0, stream>>>(u1b, pku);
  k_packa<64, 6, 6, 16><<<dim3(6144), TPB, 0, stream>>>(e1b, pke);
  k_subm_dp<64, 6, 6, 16, 2, 4><<<dim3(1024), TPB, 0, stream>>>(pku, pke, pw_dec1, bn_dec1, m1, ztile, c1b);
  k_up_b<64, 32, 7, 7><<<g(524288LL * 8), TPB, 0, stream>>>(c1b, w_up0, list0, cnt0, u0b);
  k_subm_m<32, 32, 32, 7, 7, 32><<<dim3(2048), TPB, 0, stream>>>(u0b, e0b, pw_dec0, bn_dec0, list0, cnt0, zb, c0b);
  // head
  k_head_b<<<g(524288LL * 45), TPB, 0, stream>>>(c0b, w_head, b_head, list0, cnt0, (float*)d_out);
}

// Round 17
// 946.928 us; speedup vs baseline: 1.1012x; 1.1012x over previous
//
#include <hip/hip_runtime.h>
#include <math.h>

#define TPB 256

typedef __attribute__((ext_vector_type(8))) short short8v;
typedef __attribute__((ext_vector_type(4))) short short4v;
typedef __attribute__((ext_vector_type(4))) float f32x4;

// ---------------------------------------------------------------------------
// bf16 helpers
// ---------------------------------------------------------------------------
__device__ __forceinline__ float b2f(unsigned short u) {
  union { unsigned i; float f; } x; x.i = ((unsigned)u) << 16; return x.f;
}
__device__ __forceinline__ unsigned short f2b(float f) {
  union { float f; unsigned i; } x; x.f = f;
  unsigned r = (x.i + 0x7fffu + ((x.i >> 16) & 1u)) >> 16;
  return (unsigned short)r;
}

__device__ __forceinline__ float4 ld4(const float* p) { return *(const float4*)p; }

__device__ __forceinline__ void fma4(float s, const float4 w, float4& a) {
  a.x = fmaf(s, w.x, a.x); a.y = fmaf(s, w.y, a.y);
  a.z = fmaf(s, w.z, a.z); a.w = fmaf(s, w.w, a.w);
}

template<int Co>
__device__ __forceinline__ float4 bn_relu4(float4 a, const float* __restrict__ bn, int cg) {
  const float4 g = ld4(bn + cg * 4);
  const float4 b = ld4(bn + Co + cg * 4);
  const float4 m = ld4(bn + 2 * Co + cg * 4);
  const float4 v = ld4(bn + 3 * Co + cg * 4);
  float4 r;
  r.x = fmaxf((a.x - m.x) * (g.x * rsqrtf(v.x + 1e-5f)) + b.x, 0.f);
  r.y = fmaxf((a.y - m.y) * (g.y * rsqrtf(v.y + 1e-5f)) + b.y, 0.f);
  r.z = fmaxf((a.z - m.z) * (g.z * rsqrtf(v.z + 1e-5f)) + b.z, 0.f);
  r.w = fmaxf((a.w - m.w) * (g.w * rsqrtf(v.w + 1e-5f)) + b.w, 0.f);
  return r;
}

// ---------------------------------------------------------------------------
// mask pyramid
// ---------------------------------------------------------------------------
template<int LW, int LH, int D>
__global__ void __launch_bounds__(TPB) k_maskpool(const float* __restrict__ mf,
                                                  float* __restrict__ mc) {
  constexpr int W = 1 << LW, H = 1 << LH;
  constexpr int total = D * H * W;
  const int v = blockIdx.x * TPB + threadIdx.x;
  if (v >= total) return;
  const int w = v & (W - 1), h = (v >> LW) & (H - 1), d = v >> (LW + LH);
  float mp = 0.f;
  #pragma unroll
  for (int dz = 0; dz < 2; ++dz)
    #pragma unroll
    for (int hz = 0; hz < 2; ++hz)
      #pragma unroll
      for (int wz = 0; wz < 2; ++wz)
        mp = fmaxf(mp, mf[((((2*d+dz) << (LH+1)) + (2*h+hz)) << (LW+1)) + (2*w+wz)]);
  mc[v] = mp;
}

// ---------------------------------------------------------------------------
// deterministic ordered compaction: count -> scan -> fill
// ---------------------------------------------------------------------------
__global__ void __launch_bounds__(TPB) k_count(const float* __restrict__ m, int total,
                                               int* __restrict__ bcount) {
  const int v = blockIdx.x * TPB + threadIdx.x;
  const bool act = (v < total) && (m[v] != 0.f);
  const unsigned long long b = __ballot(act);
  __shared__ int wc[TPB / 64];
  const int wid = threadIdx.x >> 6;
  if ((threadIdx.x & 63) == 0) wc[wid] = __popcll(b);
  __syncthreads();
  if (threadIdx.x == 0) bcount[blockIdx.x] = wc[0] + wc[1] + wc[2] + wc[3];
}

__global__ void __launch_bounds__(1024) k_scan(const int* __restrict__ bc, int nb,
                                               int* __restrict__ boff, int* __restrict__ total) {
  __shared__ int part[1024];
  const int t = threadIdx.x;
  const int a0 = (2 * t     < nb) ? bc[2 * t]     : 0;
  const int a1 = (2 * t + 1 < nb) ? bc[2 * t + 1] : 0;
  part[t] = a0 + a1;
  __syncthreads();
  for (int off = 1; off < 1024; off <<= 1) {
    const int tmp = (t >= off) ? part[t - off] : 0;
    __syncthreads();
    part[t] += tmp;
    __syncthreads();
  }
  const int excl = (t == 0) ? 0 : part[t - 1];
  if (2 * t     < nb) boff[2 * t]     = excl;
  if (2 * t + 1 < nb) boff[2 * t + 1] = excl + a0;
  if (t == 1023) *total = part[1023];
}

__global__ void __launch_bounds__(TPB) k_fill(const float* __restrict__ m, int total,
                                              const int* __restrict__ boff,
                                              int* __restrict__ list) {
  const int v = blockIdx.x * TPB + threadIdx.x;
  const bool act = (v < total) && (m[v] != 0.f);
  const unsigned long long b = __ballot(act);
  const int wid = threadIdx.x >> 6, lane = threadIdx.x & 63;
  __shared__ int wc[TPB / 64];
  __shared__ int wbase[TPB / 64];
  if (lane == 0) wc[wid] = __popcll(b);
  __syncthreads();
  if (threadIdx.x == 0) {
    int s = boff[blockIdx.x];
    #pragma unroll
    for (int i = 0; i < TPB / 64; ++i) { wbase[i] = s; s += wc[i]; }
  }
  __syncthreads();
  if (act) {
    const int rank = __popcll(b & ((1ull << lane) - 1ull));
    list[wbase[wid] + rank] = v;
  }
}

// ---------------------------------------------------------------------------
// x: fp32 [NV][20] -> bf16 [NV][32]
// ---------------------------------------------------------------------------
__global__ void __launch_bounds__(TPB) k_cvtx(const float* __restrict__ x,
                                              unsigned short* __restrict__ xb, int NV) {
  const int v = blockIdx.x * TPB + threadIdx.x;
  if (v >= NV) return;
  const float* r = x + (size_t)v * 20;
  unsigned short* o = xb + (size_t)v * 32;
  #pragma unroll
  for (int c4 = 0; c4 < 5; ++c4) {
    const float4 f = ld4(r + c4 * 4);
    short4v s; s[0] = (short)f2b(f.x); s[1] = (short)f2b(f.y);
    s[2] = (short)f2b(f.z); s[3] = (short)f2b(f.w);
    *(short4v*)(o + c4 * 4) = s;
  }
  const short4v z = {0, 0, 0, 0};
  *(short4v*)(o + 20) = z; *(short4v*)(o + 24) = z; *(short4v*)(o + 28) = z;
}

// ---------------------------------------------------------------------------
// weight pack: fp32 [27][C1r+C2][Co] -> bf16 MFMA-B fragments.
// ---------------------------------------------------------------------------
template<int C1r, int C1p, int C2, int Co>
__global__ void __launch_bounds__(TPB) k_packw(const float* __restrict__ w,
                                               unsigned short* __restrict__ pw) {
  constexpr int NT = Co / 16;
  constexpr int NKC = (C1p + C2) / 32;
  constexpr int total = 27 * NT * NKC * 512;
  const int idx = blockIdx.x * TPB + threadIdx.x;
  if (idx >= total) return;
  const int j = idx & 7;
  const int l = (idx >> 3) & 63;
  int rest = idx >> 9;
  const int kc = rest % NKC; rest /= NKC;
  const int nt = rest % NT;
  const int t = rest / NT;
  const int k = kc * 32 + ((l >> 4) << 3) + j;
  const int n = nt * 16 + (l & 15);
  int ksrc;
  if (k < C1p) ksrc = (k < C1r) ? k : -1;
  else         ksrc = C1r + (k - C1p);
  const float val = (ksrc < 0) ? 0.f : w[((size_t)t * (C1r + C2) + ksrc) * Co + n];
  pw[idx] = f2b(val);
}

// ---------------------------------------------------------------------------
// activation A-pack (dst-indexed, writes its own zeros -> no memset needed)
// ---------------------------------------------------------------------------
template<int C, int LW, int LH, int D>
__global__ void __launch_bounds__(TPB) k_packa(const unsigned short* __restrict__ xb,
                                               unsigned short* __restrict__ pka) {
  constexpr int W = 1 << LW, H = 1 << LH;
  constexpr int NKC = C / 32;
  constexpr int NWT = W / 16;
  const int total = 3 * D * H * NWT * NKC * 64;
  int idx = blockIdx.x * TPB + threadIdx.x;
  if (idx >= total) return;
  const int l = idx & 63; idx >>= 6;
  const int kc = idx % NKC; idx /= NKC;
  const int wt = idx % NWT; idx /= NWT;
  const int h = idx % H; idx /= H;
  const int d = idx % D;
  const int s = idx / D;
  const int lm = l & 15, lg = l >> 4;
  const int w = wt * 16 + lm + s - 1;
  unsigned short* dst = pka +
    ((((size_t)(s * D + d) * H + h) * NWT + wt) * NKC + kc) * 512 + l * 8;
  if ((unsigned)w < (unsigned)W) {
    const unsigned short* src = xb + ((size_t)((((d << LH) + h) << LW) + w)) * C + kc * 32 + lg * 8;
    *(short4v*)dst = *(const short4v*)src;
    *(short4v*)(dst + 4) = *(const short4v*)(src + 4);
  } else {
    const short4v z = {0, 0, 0, 0};
    *(short4v*)dst = z;
    *(short4v*)(dst + 4) = z;
  }
}

// ---------------------------------------------------------------------------
// DENSE subm via MFMA with PACKED A + A-reuse across ALL NT co-tiles.
// ---------------------------------------------------------------------------
template<int Co, int LW, int LH, int D, int NKC1, int NKC>
__global__ void __launch_bounds__(TPB) k_subm_dp(
    const unsigned short* __restrict__ pk1, const unsigned short* __restrict__ pk2,
    const unsigned short* __restrict__ pw, const float* __restrict__ bn,
    const float* __restrict__ mask, const unsigned short* __restrict__ ztile,
    unsigned short* __restrict__ out)
{
  constexpr int NT = Co / 16;
  constexpr int H = 1 << LH, W = 1 << LW;
  constexpr int NWT = W / 16;
  const int wv = threadIdx.x >> 6, l = threadIdx.x & 63;
  const int lm = l & 15, lg = l >> 4;
  const int total = D * H * NWT;

  for (int u = blockIdx.x * 4 + wv; u < total; u += gridDim.x * 4) {
    int rest = u;
    const int wt = rest % NWT; rest /= NWT;
    const int h = rest & (H - 1);
    const int d = rest >> LH;
    f32x4 acc[NT];
    #pragma unroll
    for (int nt = 0; nt < NT; ++nt) acc[nt] = (f32x4){0.f, 0.f, 0.f, 0.f};

    for (int t = 0; t < 27; ++t) {
      const int kd = t / 9, kh = (t / 3) % 3, s = t % 3;
      const int zd = d + kd - 1, zh = h + kh - 1;
      const bool inb = ((unsigned)zd < (unsigned)D) & ((unsigned)zh < (unsigned)H);
      const size_t tile = (((size_t)(s * D + (inb ? zd : 0)) * H + (inb ? zh : 0)) * NWT + wt);
      #pragma unroll
      for (int kc = 0; kc < NKC; ++kc) {
        const unsigned short* src;
        if (kc < NKC1)
          src = inb ? pk1 + (tile * NKC1 + kc) * 512 : ztile;
        else
          src = inb ? pk2 + (tile * (NKC - NKC1) + (kc - NKC1)) * 512 : ztile;
        const short8v a = *(const short8v*)(src + l * 8);
        #pragma unroll
        for (int nt = 0; nt < NT; ++nt) {
          const short8v b = *(const short8v*)(pw + ((((size_t)t * NT + nt) * NKC + kc) << 9) + l * 8);
          acc[nt] = __builtin_amdgcn_mfma_f32_16x16x32_bf16(a, b, acc[nt], 0, 0, 0);
        }
      }
    }

    #pragma unroll
    for (int nt = 0; nt < NT; ++nt) {
      const int co = nt * 16 + lm;
      const float sc = bn[co] * rsqrtf(bn[3 * Co + co] + 1e-5f);
      const float sh = bn[Co + co] - bn[2 * Co + co] * sc;
      #pragma unroll
      for (int i = 0; i < 4; ++i) {
        const int wo = wt * 16 + lg * 4 + i;
        const int v = (((d << LH) + h) << LW) + wo;
        const float y = fmaxf(acc[nt][i] * sc + sh, 0.f) * mask[v];
        out[(size_t)v * Co + co] = f2b(y);
      }
    }
  }
}

// ---------------------------------------------------------------------------
// subm via MFMA (sparse list, full 27 taps): exact R8 body.
// ---------------------------------------------------------------------------
template<int C1p, int C2, int Co, int LW, int LH, int D>
__global__ void __launch_bounds__(TPB) k_subm_m(
    const unsigned short* __restrict__ xb1, const unsigned short* __restrict__ xb2,
    const unsigned short* __restrict__ pw, const float* __restrict__ bn,
    const int* __restrict__ list, const int* __restrict__ cnt,
    const unsigned short* __restrict__ zb, unsigned short* __restrict__ out)
{
  constexpr int NT = Co / 16;
  constexpr int NKC1 = C1p / 32;
  constexpr int NKC = (C1p + C2) / 32;
  constexpr int MH = (NT >= 4) ? 1 : 2;
  constexpr int NTPW = (NT >= 4) ? NT / 4 : 1;
  constexpr int MVB = 32 * MH;
  constexpr int H = 1 << LH, W = 1 << LW;

  const int n = *cnt;
  if (n == 0) return;
  const int nmt = (n + MVB - 1) / MVB;
  const int wv = threadIdx.x >> 6, l = threadIdx.x & 63;
  const int mhalf = (MH == 2) ? (wv >> 1) : 0;
  const int nt0   = (MH == 2) ? (wv & 1) : wv * NTPW;
  const int lm = l & 15, lg = l >> 4;

  for (int mt = blockIdx.x; mt < nmt; mt += gridDim.x) {
    const int r0 = mt * MVB + mhalf * 32;
    int wx[2], hy[2], dzz[2];
    #pragma unroll
    for (int h2 = 0; h2 < 2; ++h2) {
      const int g = min(r0 + h2 * 16 + lm, n - 1);
      const int v = list[g];
      wx[h2] = v & (W - 1); hy[h2] = (v >> LW) & (H - 1); dzz[h2] = v >> (LW + LH);
    }
    f32x4 acc[NTPW][2];
    #pragma unroll
    for (int q = 0; q < NTPW; ++q)
      #pragma unroll
      for (int h2 = 0; h2 < 2; ++h2)
        acc[q][h2] = (f32x4){0.f, 0.f, 0.f, 0.f};

    for (int t = 0; t < 27; ++t) {
      const int kd = t / 9, kh = (t / 3) % 3, kw = t % 3;
      const unsigned short* p1[2];
      const unsigned short* p2[2];
      #pragma unroll
      for (int h2 = 0; h2 < 2; ++h2) {
        const int zd0 = dzz[h2] + kd - 1, zh0 = hy[h2] + kh - 1, zw0 = wx[h2] + kw - 1;
        const bool inb = ((unsigned)zd0 < (unsigned)D) &
                         ((unsigned)zh0 < (unsigned)H) &
                         ((unsigned)zw0 < (unsigned)W);
        const int zd = min(max(zd0, 0), D - 1);
        const int zh = min(max(zh0, 0), H - 1);
        const int zw = min(max(zw0, 0), W - 1);
        const int nv = (((zd << LH) + zh) << LW) + zw;
        p1[h2] = (inb ? xb1 + (size_t)nv * C1p : zb) + lg * 8;
        if constexpr (C2 > 0) p2[h2] = (inb ? xb2 + (size_t)nv * C2 : zb) + lg * 8;
      }
      #pragma unroll
      for (int kc = 0; kc < NKC; ++kc) {
        short8v a0, a1;
        if (C2 == 0 || kc < NKC1) {
          const int coff = kc * 32;
          a0 = *(const short8v*)(p1[0] + coff);
          a1 = *(const short8v*)(p1[1] + coff);
        } else {
          const int coff = (kc - NKC1) * 32;
          a0 = *(const short8v*)(p2[0] + coff);
          a1 = *(const short8v*)(p2[1] + coff);
        }
        #pragma unroll
        for (int q = 0; q < NTPW; ++q) {
          const int nt = nt0 + q;
          const short8v b = *(const short8v*)(pw + ((((size_t)t * NT + nt) * NKC + kc) << 9) + l * 8);
          acc[q][0] = __builtin_amdgcn_mfma_f32_16x16x32_bf16(a0, b, acc[q][0], 0, 0, 0);
          acc[q][1] = __builtin_amdgcn_mfma_f32_16x16x32_bf16(a1, b, acc[q][1], 0, 0, 0);
        }
      }
    }
    #pragma unroll
    for (int q = 0; q < NTPW; ++q) {
      const int nt = nt0 + q;
      const int co = nt * 16 + lm;
      const float sc = bn[co] * rsqrtf(bn[3 * Co + co] + 1e-5f);
      const float sh = bn[Co + co] - bn[2 * Co + co] * sc;
      #pragma unroll
      for (int h2 = 0; h2 < 2; ++h2)
        #pragma unroll
        for (int i = 0; i < 4; ++i) {
          const int g = r0 + h2 * 16 + lg * 4 + i;
          if (g < n) {
            const int v = list[g];
            const float y = fmaxf(acc[q][h2][i] * sc + sh, 0.f);
            out[(size_t)v * Co + co] = f2b(y);
          }
        }
    }
  }
}

// ---------------------------------------------------------------------------
// subm via MFMA, TAP-SPLIT (deep layers): exact R8 body.
// ---------------------------------------------------------------------------
template<int C1p, int C2, int Co, int LW, int LH, int D, int NSPLIT, int CAP>
__global__ void __launch_bounds__(TPB) k_subm_mp(
    const unsigned short* __restrict__ xb1, const unsigned short* __restrict__ xb2,
    const unsigned short* __restrict__ pw,
    const int* __restrict__ list, const int* __restrict__ cnt,
    const unsigned short* __restrict__ zb, float* __restrict__ pbuf)
{
  constexpr int NT = Co / 16;
  constexpr int NKC1 = C1p / 32;
  constexpr int NKC = (C1p + C2) / 32;
  constexpr int MH = (NT >= 4) ? 1 : 2;
  constexpr int NTPW = (NT >= 4) ? NT / 4 : 1;
  constexpr int MVB = 32 * MH;
  constexpr int TPS = 27 / NSPLIT;
  constexpr int H = 1 << LH, W = 1 << LW;

  const int n = *cnt;
  if (n == 0) return;
  const int nmt = (n + MVB - 1) / MVB;
  const int s = blockIdx.y;
  const int wv = threadIdx.x >> 6, l = threadIdx.x & 63;
  const int mhalf = (MH == 2) ? (wv >> 1) : 0;
  const int nt0   = (MH == 2) ? (wv & 1) : wv * NTPW;
  const int lm = l & 15, lg = l >> 4;

  for (int mt = blockIdx.x; mt < nmt; mt += gridDim.x) {
    const int r0 = mt * MVB + mhalf * 32;
    int wx[2], hy[2], dzz[2];
    #pragma unroll
    for (int h2 = 0; h2 < 2; ++h2) {
      const int g = min(r0 + h2 * 16 + lm, n - 1);
      const int v = list[g];
      wx[h2] = v & (W - 1); hy[h2] = (v >> LW) & (H - 1); dzz[h2] = v >> (LW + LH);
    }
    f32x4 acc[NTPW][2];
    #pragma unroll
    for (int q = 0; q < NTPW; ++q)
      #pragma unroll
      for (int h2 = 0; h2 < 2; ++h2)
        acc[q][h2] = (f32x4){0.f, 0.f, 0.f, 0.f};

    for (int t = s * TPS; t < (s + 1) * TPS; ++t) {
      const int kd = t / 9, kh = (t / 3) % 3, kw = t % 3;
      const unsigned short* p1[2];
      const unsigned short* p2[2];
      #pragma unroll
      for (int h2 = 0; h2 < 2; ++h2) {
        const int zd0 = dzz[h2] + kd - 1, zh0 = hy[h2] + kh - 1, zw0 = wx[h2] + kw - 1;
        const bool inb = ((unsigned)zd0 < (unsigned)D) &
                         ((unsigned)zh0 < (unsigned)H) &
                         ((unsigned)zw0 < (unsigned)W);
        const int zd = min(max(zd0, 0), D - 1);
        const int zh = min(max(zh0, 0), H - 1);
        const int zw = min(max(zw0, 0), W - 1);
        const int nv = (((zd << LH) + zh) << LW) + zw;
        p1[h2] = (inb ? xb1 + (size_t)nv * C1p : zb) + lg * 8;
        if constexpr (C2 > 0) p2[h2] = (inb ? xb2 + (size_t)nv * C2 : zb) + lg * 8;
      }
      #pragma unroll
      for (int kc = 0; kc < NKC; ++kc) {
        short8v a0, a1;
        if (C2 == 0 || kc < NKC1) {
          const int coff = kc * 32;
          a0 = *(const short8v*)(p1[0] + coff);
          a1 = *(const short8v*)(p1[1] + coff);
        } else {
          const int coff = (kc - NKC1) * 32;
          a0 = *(const short8v*)(p2[0] + coff);
          a1 = *(const short8v*)(p2[1] + coff);
        }
        #pragma unroll
        for (int q = 0; q < NTPW; ++q) {
          const int nt = nt0 + q;
          const short8v b = *(const short8v*)(pw + ((((size_t)t * NT + nt) * NKC + kc) << 9) + l * 8);
          acc[q][0] = __builtin_amdgcn_mfma_f32_16x16x32_bf16(a0, b, acc[q][0], 0, 0, 0);
          acc[q][1] = __builtin_amdgcn_mfma_f32_16x16x32_bf16(a1, b, acc[q][1], 0, 0, 0);
        }
      }
    }
    #pragma unroll
    for (int q = 0; q < NTPW; ++q) {
      const int co = (nt0 + q) * 16 + lm;
      #pragma unroll
      for (int h2 = 0; h2 < 2; ++h2)
        #pragma unroll
        for (int i = 0; i < 4; ++i) {
          const int g = r0 + h2 * 16 + lg * 4 + i;
          if (g < n)
            pbuf[((size_t)s * CAP + g) * Co + co] = acc[q][h2][i];
        }
    }
  }
}

// sum NSPLIT fp32 partials in fixed order + BN + ReLU -> bf16 out
template<int Co, int NSPLIT, int CAP>
__global__ void __launch_bounds__(TPB) k_reduce_bnb(
    const float* __restrict__ pbuf, const float* __restrict__ bn,
    const int* __restrict__ list, const int* __restrict__ cnt,
    unsigned short* __restrict__ out)
{
  constexpr int TPV = Co / 4;
  const int n = *cnt;
  const int total = n * TPV;
  for (int i = blockIdx.x * TPB + threadIdx.x; i < total; i += gridDim.x * TPB) {
    const int a = i / TPV;
    const int cg = i % TPV;
    float4 acc = make_float4(0.f, 0.f, 0.f, 0.f);
    #pragma unroll
    for (int s = 0; s < NSPLIT; ++s) {
      const float4 p = ld4(pbuf + ((size_t)s * CAP + a) * Co + cg * 4);
      acc.x += p.x; acc.y += p.y; acc.z += p.z; acc.w += p.w;
    }
    const int v = list[a];
    const float4 r = bn_relu4<Co>(acc, bn, cg);
    short4v o; o[0] = (short)f2b(r.x); o[1] = (short)f2b(r.y);
    o[2] = (short)f2b(r.z); o[3] = (short)f2b(r.w);
    *(short4v*)(out + (size_t)v * Co + cg * 4) = o;
  }
}

// ---------------------------------------------------------------------------
// down: 2x2x2 stride-2 conv + BN + ReLU; bf16 acts, fp32 weights/math
// ---------------------------------------------------------------------------
template<int Ci, int Co, int LW, int LH, int D>
__global__ void __launch_bounds__(TPB) k_down_b(
    const unsigned short* __restrict__ x, const float* __restrict__ wgt,
    const float* __restrict__ bn, const float* __restrict__ mfine,
    const int* __restrict__ list, const int* __restrict__ cnt,
    unsigned short* __restrict__ out)
{
  constexpr int TPV = Co / 4;
  constexpr int H = 1 << LH, W = 1 << LW;
  const int n = *cnt;
  const int total = n * TPV;
  for (int i = blockIdx.x * TPB + threadIdx.x; i < total; i += gridDim.x * TPB) {
    const int a = i / TPV;
    const int cg = i % TPV;
    const int v = list[a];
    const int w = v & (W - 1), h = (v >> LW) & (H - 1), d = v >> (LW + LH);
    float4 acc0 = make_float4(0.f, 0.f, 0.f, 0.f);
    float4 acc1 = make_float4(0.f, 0.f, 0.f, 0.f);
    #pragma unroll
    for (int kd = 0; kd < 2; ++kd)
      #pragma unroll
      for (int kh = 0; kh < 2; ++kh)
        #pragma unroll
        for (int kw = 0; kw < 2; ++kw) {
          const int nv = ((((2*d+kd) << (LH+1)) + (2*h+kh)) << (LW+1)) + (2*w+kw);
          if (mfine[nv] == 0.f) continue;
          const int tap = (kd * 2 + kh) * 2 + kw;
          const float4* __restrict__ wp = (const float4*)wgt + (size_t)tap * Ci * TPV + cg;
          const unsigned short* row = x + (size_t)nv * Ci;
          #pragma unroll
          for (int c8 = 0; c8 < Ci / 8; ++c8) {
            const short8v s = *(const short8v*)(row + c8 * 8);
            fma4(b2f((unsigned short)s[0]), wp[(c8 * 8 + 0) * TPV], acc0);
            fma4(b2f((unsigned short)s[1]), wp[(c8 * 8 + 1) * TPV], acc1);
            fma4(b2f((unsigned short)s[2]), wp[(c8 * 8 + 2) * TPV], acc0);
            fma4(b2f((unsigned short)s[3]), wp[(c8 * 8 + 3) * TPV], acc1);
            fma4(b2f((unsigned short)s[4]), wp[(c8 * 8 + 4) * TPV], acc0);
            fma4(b2f((unsigned short)s[5]), wp[(c8 * 8 + 5) * TPV], acc1);
            fma4(b2f((unsigned short)s[6]), wp[(c8 * 8 + 6) * TPV], acc0);
            fma4(b2f((unsigned short)s[7]), wp[(c8 * 8 + 7) * TPV], acc1);
          }
        }
    float4 acc;
    acc.x = acc0.x + acc1.x; acc.y = acc0.y + acc1.y;
    acc.z = acc0.z + acc1.z; acc.w = acc0.w + acc1.w;
    const float4 r = bn_relu4<Co>(acc, bn, cg);
    short4v o; o[0] = (short)f2b(r.x); o[1] = (short)f2b(r.y);
    o[2] = (short)f2b(r.z); o[3] = (short)f2b(r.w);
    *(short4v*)(out + (size_t)v * Co + cg * 4) = o;
  }
}

// ---------------------------------------------------------------------------
// up: 1-tap conv_transpose; bf16 acts, fp32 weights/math
// ---------------------------------------------------------------------------
template<int Ci, int Co, int LW, int LH>
__global__ void __launch_bounds__(TPB) k_up_b(
    const unsigned short* __restrict__ x, const float* __restrict__ wgt,
    const int* __restrict__ list, const int* __restrict__ cnt,
    unsigned short* __restrict__ out)
{
  constexpr int TPV = Co / 4;
  constexpr int H = 1 << LH, W = 1 << LW;
  const int n = *cnt;
  const int total = n * TPV;
  for (int i = blockIdx.x * TPB + threadIdx.x; i < total; i += gridDim.x * TPB) {
    const int a = i / TPV;
    const int cg = i % TPV;
    const int v = list[a];
    const int w = v & (W - 1), h = (v >> LW) & (H - 1), d = v >> (LW + LH);
    const int kd = 1 - (d & 1), kh = 1 - (h & 1), kw = 1 - (w & 1);
    const int nv = ((((d >> 1) << (LH - 1)) + (h >> 1)) << (LW - 1)) + (w >> 1);
    const int tap = (kd * 2 + kh) * 2 + kw;
    const float4* __restrict__ wp = (const float4*)wgt + (size_t)tap * Ci * TPV + cg;
    const unsigned short* row = x + (size_t)nv * Ci;
    float4 acc0 = make_float4(0.f, 0.f, 0.f, 0.f);
    float4 acc1 = make_float4(0.f, 0.f, 0.f, 0.f);
    #pragma unroll
    for (int c8 = 0; c8 < Ci / 8; ++c8) {
      const short8v s = *(const short8v*)(row + c8 * 8);
      fma4(b2f((unsigned short)s[0]), wp[(c8 * 8 + 0) * TPV], acc0);
      fma4(b2f((unsigned short)s[1]), wp[(c8 * 8 + 1) * TPV], acc1);
      fma4(b2f((unsigned short)s[2]), wp[(c8 * 8 + 2) * TPV], acc0);
      fma4(b2f((unsigned short)s[3]), wp[(c8 * 8 + 3) * TPV], acc1);
      fma4(b2f((unsigned short)s[4]), wp[(c8 * 8 + 4) * TPV], acc0);
      fma4(b2f((unsigned short)s[5]), wp[(c8 * 8 + 5) * TPV], acc1);
      fma4(b2f((unsigned short)s[6]), wp[(c8 * 8 + 6) * TPV], acc0);
      fma4(b2f((unsigned short)s[7]), wp[(c8 * 8 + 7) * TPV], acc1);
    }
    short4v o;
    o[0] = (short)f2b(acc0.x + acc1.x); o[1] = (short)f2b(acc0.y + acc1.y);
    o[2] = (short)f2b(acc0.z + acc1.z); o[3] = (short)f2b(acc0.w + acc1.w);
    *(short4v*)(out + (size_t)v * Co + cg * 4) = o;
  }
}

// ---------------------------------------------------------------------------
// head: bf16 c0, fp32 weights; scatter into 5 output regions
// ---------------------------------------------------------------------------
__global__ void __launch_bounds__(TPB) k_head_b(
    const unsigned short* __restrict__ c0, const float* __restrict__ wh,
    const float* __restrict__ bh, const int* __restrict__ list,
    const int* __restrict__ cnt, float* __restrict__ out)
{
  __shared__ float sw[32 * 45];
  __shared__ float sb[45];
  for (int t = threadIdx.x; t < 32 * 45; t += TPB) sw[t] = wh[t];
  if (threadIdx.x < 45) sb[threadIdx.x] = bh[threadIdx.x];
  __syncthreads();
  const int n = *cnt;
  const int total = n * 45;
  const size_t NV = 524288;
  for (int i = blockIdx.x * TPB + threadIdx.x; i < total; i += gridDim.x * TPB) {
    const int a = i / 45;
    const int j = i % 45;
    const int v = list[a];
    const unsigned short* cp = c0 + (size_t)v * 32;
    float a0 = 0.f, a1 = 0.f;
    #pragma unroll
    for (int c8 = 0; c8 < 4; ++c8) {
      const short8v s = *(const short8v*)(cp + c8 * 8);
      a0 = fmaf(b2f((unsigned short)s[0]), sw[(c8 * 8 + 0) * 45 + j], a0);
      a1 = fmaf(b2f((unsigned short)s[1]), sw[(c8 * 8 + 1) * 45 + j], a1);
      a0 = fmaf(b2f((unsigned short)s[2]), sw[(c8 * 8 + 2) * 45 + j], a0);
      a1 = fmaf(b2f((unsigned short)s[3]), sw[(c8 * 8 + 3) * 45 + j], a1);
      a0 = fmaf(b2f((unsigned short)s[4]), sw[(c8 * 8 + 4) * 45 + j], a0);
      a1 = fmaf(b2f((unsigned short)s[5]), sw[(c8 * 8 + 5) * 45 + j], a1);
      a0 = fmaf(b2f((unsigned short)s[6]), sw[(c8 * 8 + 6) * 45 + j], a0);
      a1 = fmaf(b2f((unsigned short)s[7]), sw[(c8 * 8 + 7) * 45 + j], a1);
    }
    const float val = a0 + a1 + sb[j];
    const int k = j / 9, r = j % 9;
    if (r < 3)
      out[(size_t)v * 15 + k * 3 + r] = val;
    else if (r < 6)
      out[NV * 15 + (size_t)v * 15 + k * 3 + (r - 3)] = fminf(fmaxf(val, -5.f), 3.f);
    else if (r == 6)
      out[NV * 30 + (size_t)v * 5 + k] = val;
    else if (r == 7)
      out[NV * 35 + (size_t)v * 5 + k] = val;
    else
      out[NV * 40 + (size_t)v * 5 + k] = val;
  }
}

// ---------------------------------------------------------------------------
extern "C" void kernel_launch(void* const* d_in, const int* in_sizes, int n_in,
                              void* d_out, int out_size, void* d_ws, size_t ws_size,
                              hipStream_t stream)
{
  (void)in_sizes; (void)n_in;

  const float* x        = (const float*)d_in[0];
  const float* mask0    = (const float*)d_in[1];
  const float* w_enc0   = (const float*)d_in[2];
  const float* bn_enc0  = (const float*)d_in[3];
  const float* w_down0  = (const float*)d_in[4];
  const float* bn_down0 = (const float*)d_in[5];
  const float* w_enc1   = (const float*)d_in[6];
  const float* bn_enc1  = (const float*)d_in[7];
  const float* w_down1  = (const float*)d_in[8];
  const float* bn_down1 = (const float*)d_in[9];
  const float* w_enc2   = (const float*)d_in[10];
  const float* bn_enc2  = (const float*)d_in[11];
  const float* w_down2  = (const float*)d_in[12];
  const float* bn_down2 = (const float*)d_in[13];
  const float* w_bott   = (const float*)d_in[14];
  const float* bn_bott  = (const float*)d_in[15];
  const float* w_up2    = (const float*)d_in[16];
  const float* w_dec2   = (const float*)d_in[17];
  const float* bn_dec2  = (const float*)d_in[18];
  const float* w_up1    = (const float*)d_in[19];
  const float* w_dec1   = (const float*)d_in[20];
  const float* bn_dec1  = (const float*)d_in[21];
  const float* w_up0    = (const float*)d_in[22];
  const float* w_dec0   = (const float*)d_in[23];
  const float* bn_dec0  = (const float*)d_in[24];
  const float* w_head   = (const float*)d_in[25];
  const float* b_head   = (const float*)d_in[26];

  char* ws = (char*)d_ws;
  size_t o = 0;
  auto takeB = [&](size_t bytes) { char* p = ws + o; o += (bytes + 255) & ~(size_t)255; return p; };
  auto takeU = [&](size_t elems) { return (unsigned short*)takeB(elems * 2); };
  auto takeF = [&](size_t elems) { return (float*)takeB(elems * 4); };
  auto takeI = [&](size_t elems) { return (int*)takeB(elems * 4); };

  int*   cnt   = takeI(16);
  int*   bcnt  = takeI(2048);
  int*   boff  = takeI(2048);
  int*   list0 = takeI(524288);
  int*   list1 = takeI(65536);
  int*   list2 = takeI(8192);
  int*   list3 = takeI(1024);
  float* m1    = takeF(65536);
  float* m2    = takeF(8192);
  float* m3    = takeF(1024);
  unsigned short* zb    = takeU(256);
  unsigned short* ztile = takeU(512);
  float* pbuf = takeF(3145728);            // K-split partials (deep layers)
  // packed weights (bf16)
  unsigned short* pw_enc0 = takeU(27648);
  unsigned short* pw_enc1 = takeU(110592);
  unsigned short* pw_enc2 = takeU(442368);
  unsigned short* pw_bott = takeU(1769472);
  unsigned short* pw_dec2 = takeU(884736);
  unsigned short* pw_dec1 = takeU(221184);
  unsigned short* pw_dec0 = takeU(55296);
  // packed-A region for L1 dense layers (enc1 aliases dec1's first half)
  unsigned short* pkbuf = takeU(25165824);
  unsigned short* pk1 = pkbuf;             // enc1 (12.58M)
  unsigned short* pke = pkbuf;             // dec1 skip  (12.58M)
  unsigned short* pku = pkbuf + 12582912;  // dec1 up    (12.58M)
  // bf16 activations
  unsigned short* xb  = takeU(16777216);
  unsigned short* e0b = takeU(16777216);
  unsigned short* d0b = takeU(4194304);    // reused as u1b
  unsigned short* e1b = takeU(4194304);
  unsigned short* d1b = takeU(1048576);    // reused as u2b
  unsigned short* e2b = takeU(1048576);
  unsigned short* d2b = takeU(262144);
  unsigned short* bbb = takeU(262144);
  unsigned short* c2b = takeU(1048576);
  unsigned short* c1b = takeU(4194304);
  unsigned short* u0b = takeU(16777216);
  unsigned short* c0b = takeU(16777216);
  if (o > ws_size) return;
  unsigned short* u1b = d0b;
  unsigned short* u2b = d1b;
  int* cnt0 = cnt, *cnt1 = cnt + 1, *cnt2 = cnt + 2, *cnt3 = cnt + 3;

  hipMemsetAsync(d_out, 0, (size_t)out_size * sizeof(float), stream);
  hipMemsetAsync(zb, 0, 256 * 2, stream);
  hipMemsetAsync(ztile, 0, 512 * 2, stream);
  hipMemsetAsync(e0b, 0, 16777216ull * 2, stream);
  hipMemsetAsync(d0b, 0, 4194304ull * 2, stream);
  hipMemsetAsync(d1b, 0, 1048576ull * 2, stream);
  hipMemsetAsync(e2b, 0, 1048576ull * 2, stream);
  hipMemsetAsync(d2b, 0, 262144ull * 2, stream);
  hipMemsetAsync(u0b, 0, 16777216ull * 2, stream);

  auto g = [](long long upper) {
    unsigned b = (unsigned)((upper + TPB - 1) / TPB);
    return dim3(b > 4096u ? 4096u : (b ? b : 1u));
  };

  // weight packs + x convert
  k_packw<20, 32, 0, 32><<<g(27648), TPB, 0, stream>>>(w_enc0, pw_enc0);
  k_packw<64, 64, 0, 64><<<g(110592), TPB, 0, stream>>>(w_enc1, pw_enc1);
  k_packw<128, 128, 0, 128><<<g(442368), TPB, 0, stream>>>(w_enc2, pw_enc2);
  k_packw<256, 256, 0, 256><<<g(1769472), TPB, 0, stream>>>(w_bott, pw_bott);
  k_packw<128, 128, 128, 128><<<g(884736), TPB, 0, stream>>>(w_dec2, pw_dec2);
  k_packw<64, 64, 64, 64><<<g(221184), TPB, 0, stream>>>(w_dec1, pw_dec1);
  k_packw<32, 32, 32, 32><<<g(55296), TPB, 0, stream>>>(w_dec0, pw_dec0);
  k_cvtx<<<dim3(524288 / TPB), TPB, 0, stream>>>(x, xb, 524288);

  // mask pyramid + ordered compaction
  k_maskpool<6, 6, 16><<<g(65536), TPB, 0, stream>>>(mask0, m1);
  k_maskpool<5, 5, 8><<<g(8192), TPB, 0, stream>>>(m1, m2);
  k_maskpool<4, 4, 4><<<g(1024), TPB, 0, stream>>>(m2, m3);
  auto compact = [&](const float* m, int total, int* list, int* cptr) {
    const int nb = total / TPB;
    k_count<<<dim3((unsigned)nb), TPB, 0, stream>>>(m, total, bcnt);
    k_scan<<<dim3(1), 1024, 0, stream>>>(bcnt, nb, boff, cptr);
    k_fill<<<dim3((unsigned)nb), TPB, 0, stream>>>(m, total, boff, list);
  };
  compact(mask0, 524288, list0, cnt0);
  compact(m1,     65536, list1, cnt1);
  compact(m2,      8192, list2, cnt2);
  compact(m3,      1024, list3, cnt3);

  // encoder
  k_subm_m<32, 0, 32, 7, 7, 32><<<dim3(2048), TPB, 0, stream>>>(xb, nullptr, pw_enc0, bn_enc0, list0, cnt0, zb, e0b);
  k_down_b<32, 64, 6, 6, 16><<<g(65536LL * 16), TPB, 0, stream>>>(e0b, w_down0, bn_down0, mask0, list1, cnt1, d0b);
  // enc1: pack + dense conv (A shared across all 4 co-tiles)
  k_packa<64, 6, 6, 16><<<dim3(6144), TPB, 0, stream>>>(d0b, pk1);
  k_subm_dp<64, 6, 6, 16, 2, 2><<<dim3(1024), TPB, 0, stream>>>(pk1, nullptr, pw_enc1, bn_enc1, m1, ztile, e1b);
  k_down_b<64, 128, 5, 5, 8><<<g(8192LL * 32), TPB, 0, stream>>>(e1b, w_down1, bn_down1, m1, list2, cnt2, d1b);
  // enc2: tap-split x3
  k_subm_mp<128, 0, 128, 5, 5, 8, 3, 8192><<<dim3(256, 3), TPB, 0, stream>>>(d1b, nullptr, pw_enc2, list2, cnt2, zb, pbuf);
  k_reduce_bnb<128, 3, 8192><<<g(8192LL * 32), TPB, 0, stream>>>(pbuf, bn_enc2, list2, cnt2, e2b);
  k_down_b<128, 256, 4, 4, 4><<<g(1024LL * 64), TPB, 0, stream>>>(e2b, w_down2, bn_down2, m2, list3, cnt3, d2b);
  // bottleneck: tap-split x9
  k_subm_mp<256, 0, 256, 4, 4, 4, 9, 1024><<<dim3(32, 9), TPB, 0, stream>>>(d2b, nullptr, pw_bott, list3, cnt3, zb, pbuf);
  k_reduce_bnb<256, 9, 1024><<<g(1024LL * 64), TPB, 0, stream>>>(pbuf, bn_bott, list3, cnt3, bbb);
  // decoder
  k_up_b<256, 128, 5, 5><<<g(8192LL * 32), TPB, 0, stream>>>(bbb, w_up2, list2, cnt2, u2b);
  // dec2: tap-split x3 (concat u2|e2)
  k_subm_mp<128, 128, 128, 5, 5, 8, 3, 8192><<<dim3(256, 3), TPB, 0, stream>>>(u2b, e2b, pw_dec2, list2, cnt2, zb, pbuf);
  k_reduce_bnb<128, 3, 8192><<<g(8192LL * 32), TPB, 0, stream>>>(pbuf, bn_dec2, list2, cnt2, c2b);
  k_up_b<128, 64, 6, 6><<<g(65536LL * 16), TPB, 0, stream>>>(c2b, w_up1, list1, cnt1, u1b);
  // dec1: pack u1b+e1b, dense conv (concat u1|e1, A shared across co-tiles)
  k_packa<64, 6, 6, 16><<<dim3(6144), TPB, 0, stream>>>(u1b, pku);
  k_packa<64, 6, 6, 16><<<dim3(6144), TPB, 0, stream>>>(e1b, pke);
  k_subm_dp<64, 6, 6, 16, 2, 4><<<dim3(1024), TPB, 0, stream>>>(pku, pke, pw_dec1, bn_dec1, m1, ztile, c1b);
  k_up_b<64, 32, 7, 7><<<g(524288LL * 8), TPB, 0, stream>>>(c1b, w_up0, list0, cnt0, u0b);
  k_subm_m<32, 32, 32, 7, 7, 32><<<dim3(2048), TPB, 0, stream>>>(u0b, e0b, pw_dec0, bn_dec0, list0, cnt0, zb, c0b);
  // head
  k_head_b<<<g(524288LL * 45), TPB, 0, stream>>>(c0b, w_head, b_head, list0, cnt0, (float*)d_out);
}

// Round 18
// 944.949 us; speedup vs baseline: 1.1035x; 1.0021x over previous
//
#include <hip/hip_runtime.h>
#include <math.h>

#define TPB 256

typedef __attribute__((ext_vector_type(8))) short short8v;
typedef __attribute__((ext_vector_type(4))) short short4v;
typedef __attribute__((ext_vector_type(4))) float f32x4;

// ---------------------------------------------------------------------------
// bf16 helpers
// ---------------------------------------------------------------------------
__device__ __forceinline__ float b2f(unsigned short u) {
  union { unsigned i; float f; } x; x.i = ((unsigned)u) << 16; return x.f;
}
__device__ __forceinline__ unsigned short f2b(float f) {
  union { float f; unsigned i; } x; x.f = f;
  unsigned r = (x.i + 0x7fffu + ((x.i >> 16) & 1u)) >> 16;
  return (unsigned short)r;
}

__device__ __forceinline__ float4 ld4(const float* p) { return *(const float4*)p; }

__device__ __forceinline__ void fma4(float s, const float4 w, float4& a) {
  a.x = fmaf(s, w.x, a.x); a.y = fmaf(s, w.y, a.y);
  a.z = fmaf(s, w.z, a.z); a.w = fmaf(s, w.w, a.w);
}

template<int Co>
__device__ __forceinline__ float4 bn_relu4(float4 a, const float* __restrict__ bn, int cg) {
  const float4 g = ld4(bn + cg * 4);
  const float4 b = ld4(bn + Co + cg * 4);
  const float4 m = ld4(bn + 2 * Co + cg * 4);
  const float4 v = ld4(bn + 3 * Co + cg * 4);
  float4 r;
  r.x = fmaxf((a.x - m.x) * (g.x * rsqrtf(v.x + 1e-5f)) + b.x, 0.f);
  r.y = fmaxf((a.y - m.y) * (g.y * rsqrtf(v.y + 1e-5f)) + b.y, 0.f);
  r.z = fmaxf((a.z - m.z) * (g.z * rsqrtf(v.z + 1e-5f)) + b.z, 0.f);
  r.w = fmaxf((a.w - m.w) * (g.w * rsqrtf(v.w + 1e-5f)) + b.w, 0.f);
  return r;
}

// ---------------------------------------------------------------------------
// mask pyramid
// ---------------------------------------------------------------------------
template<int LW, int LH, int D>
__global__ void __launch_bounds__(TPB) k_maskpool(const float* __restrict__ mf,
                                                  float* __restrict__ mc) {
  constexpr int W = 1 << LW, H = 1 << LH;
  constexpr int total = D * H * W;
  const int v = blockIdx.x * TPB + threadIdx.x;
  if (v >= total) return;
  const int w = v & (W - 1), h = (v >> LW) & (H - 1), d = v >> (LW + LH);
  float mp = 0.f;
  #pragma unroll
  for (int dz = 0; dz < 2; ++dz)
    #pragma unroll
    for (int hz = 0; hz < 2; ++hz)
      #pragma unroll
      for (int wz = 0; wz < 2; ++wz)
        mp = fmaxf(mp, mf[((((2*d+dz) << (LH+1)) + (2*h+hz)) << (LW+1)) + (2*w+wz)]);
  mc[v] = mp;
}

// ---------------------------------------------------------------------------
// deterministic ordered compaction: count -> scan -> fill
// ---------------------------------------------------------------------------
__global__ void __launch_bounds__(TPB) k_count(const float* __restrict__ m, int total,
                                               int* __restrict__ bcount) {
  const int v = blockIdx.x * TPB + threadIdx.x;
  const bool act = (v < total) && (m[v] != 0.f);
  const unsigned long long b = __ballot(act);
  __shared__ int wc[TPB / 64];
  const int wid = threadIdx.x >> 6;
  if ((threadIdx.x & 63) == 0) wc[wid] = __popcll(b);
  __syncthreads();
  if (threadIdx.x == 0) bcount[blockIdx.x] = wc[0] + wc[1] + wc[2] + wc[3];
}

__global__ void __launch_bounds__(1024) k_scan(const int* __restrict__ bc, int nb,
                                               int* __restrict__ boff, int* __restrict__ total) {
  __shared__ int part[1024];
  const int t = threadIdx.x;
  const int a0 = (2 * t     < nb) ? bc[2 * t]     : 0;
  const int a1 = (2 * t + 1 < nb) ? bc[2 * t + 1] : 0;
  part[t] = a0 + a1;
  __syncthreads();
  for (int off = 1; off < 1024; off <<= 1) {
    const int tmp = (t >= off) ? part[t - off] : 0;
    __syncthreads();
    part[t] += tmp;
    __syncthreads();
  }
  const int excl = (t == 0) ? 0 : part[t - 1];
  if (2 * t     < nb) boff[2 * t]     = excl;
  if (2 * t + 1 < nb) boff[2 * t + 1] = excl + a0;
  if (t == 1023) *total = part[1023];
}

__global__ void __launch_bounds__(TPB) k_fill(const float* __restrict__ m, int total,
                                              const int* __restrict__ boff,
                                              int* __restrict__ list) {
  const int v = blockIdx.x * TPB + threadIdx.x;
  const bool act = (v < total) && (m[v] != 0.f);
  const unsigned long long b = __ballot(act);
  const int wid = threadIdx.x >> 6, lane = threadIdx.x & 63;
  __shared__ int wc[TPB / 64];
  __shared__ int wbase[TPB / 64];
  if (lane == 0) wc[wid] = __popcll(b);
  __syncthreads();
  if (threadIdx.x == 0) {
    int s = boff[blockIdx.x];
    #pragma unroll
    for (int i = 0; i < TPB / 64; ++i) { wbase[i] = s; s += wc[i]; }
  }
  __syncthreads();
  if (act) {
    const int rank = __popcll(b & ((1ull << lane) - 1ull));
    list[wbase[wid] + rank] = v;
  }
}

// ---------------------------------------------------------------------------
// x: fp32 [NV][20] -> bf16 [NV][32]
// ---------------------------------------------------------------------------
__global__ void __launch_bounds__(TPB) k_cvtx(const float* __restrict__ x,
                                              unsigned short* __restrict__ xb, int NV) {
  const int v = blockIdx.x * TPB + threadIdx.x;
  if (v >= NV) return;
  const float* r = x + (size_t)v * 20;
  unsigned short* o = xb + (size_t)v * 32;
  #pragma unroll
  for (int c4 = 0; c4 < 5; ++c4) {
    const float4 f = ld4(r + c4 * 4);
    short4v s; s[0] = (short)f2b(f.x); s[1] = (short)f2b(f.y);
    s[2] = (short)f2b(f.z); s[3] = (short)f2b(f.w);
    *(short4v*)(o + c4 * 4) = s;
  }
  const short4v z = {0, 0, 0, 0};
  *(short4v*)(o + 20) = z; *(short4v*)(o + 24) = z; *(short4v*)(o + 28) = z;
}

// ---------------------------------------------------------------------------
// weight pack: fp32 [27][C1r+C2][Co] -> bf16 MFMA-B fragments.
// ---------------------------------------------------------------------------
template<int C1r, int C1p, int C2, int Co>
__global__ void __launch_bounds__(TPB) k_packw(const float* __restrict__ w,
                                               unsigned short* __restrict__ pw) {
  constexpr int NT = Co / 16;
  constexpr int NKC = (C1p + C2) / 32;
  constexpr int total = 27 * NT * NKC * 512;
  const int idx = blockIdx.x * TPB + threadIdx.x;
  if (idx >= total) return;
  const int j = idx & 7;
  const int l = (idx >> 3) & 63;
  int rest = idx >> 9;
  const int kc = rest % NKC; rest /= NKC;
  const int nt = rest % NT;
  const int t = rest / NT;
  const int k = kc * 32 + ((l >> 4) << 3) + j;
  const int n = nt * 16 + (l & 15);
  int ksrc;
  if (k < C1p) ksrc = (k < C1r) ? k : -1;
  else         ksrc = C1r + (k - C1p);
  const float val = (ksrc < 0) ? 0.f : w[((size_t)t * (C1r + C2) + ksrc) * Co + n];
  pw[idx] = f2b(val);
}

// ---------------------------------------------------------------------------
// activation A-pack (dst-indexed, writes its own zeros -> no memset needed)
// ---------------------------------------------------------------------------
template<int C, int LW, int LH, int D>
__global__ void __launch_bounds__(TPB) k_packa(const unsigned short* __restrict__ xb,
                                               unsigned short* __restrict__ pka) {
  constexpr int W = 1 << LW, H = 1 << LH;
  constexpr int NKC = C / 32;
  constexpr int NWT = W / 16;
  const int total = 3 * D * H * NWT * NKC * 64;
  int idx = blockIdx.x * TPB + threadIdx.x;
  if (idx >= total) return;
  const int l = idx & 63; idx >>= 6;
  const int kc = idx % NKC; idx /= NKC;
  const int wt = idx % NWT; idx /= NWT;
  const int h = idx % H; idx /= H;
  const int d = idx % D;
  const int s = idx / D;
  const int lm = l & 15, lg = l >> 4;
  const int w = wt * 16 + lm + s - 1;
  unsigned short* dst = pka +
    ((((size_t)(s * D + d) * H + h) * NWT + wt) * NKC + kc) * 512 + l * 8;
  if ((unsigned)w < (unsigned)W) {
    const unsigned short* src = xb + ((size_t)((((d << LH) + h) << LW) + w)) * C + kc * 32 + lg * 8;
    *(short4v*)dst = *(const short4v*)src;
    *(short4v*)(dst + 4) = *(const short4v*)(src + 4);
  } else {
    const short4v z = {0, 0, 0, 0};
    *(short4v*)dst = z;
    *(short4v*)(dst + 4) = z;
  }
}

// ---------------------------------------------------------------------------
// DENSE subm via MFMA with PACKED A + A-reuse across ALL NT co-tiles.
// XCD-contiguous tile mapping: blocks with equal (b&7) share an XCD and get a
// contiguous (d,h) slab -> the 9 (kd,kh) neighbor re-reads hit that XCD's L2.
// ---------------------------------------------------------------------------
template<int Co, int LW, int LH, int D, int NKC1, int NKC>
__global__ void __launch_bounds__(TPB) k_subm_dp(
    const unsigned short* __restrict__ pk1, const unsigned short* __restrict__ pk2,
    const unsigned short* __restrict__ pw, const float* __restrict__ bn,
    const float* __restrict__ mask, const unsigned short* __restrict__ ztile,
    unsigned short* __restrict__ out)
{
  constexpr int NT = Co / 16;
  constexpr int H = 1 << LH, W = 1 << LW;
  constexpr int NWT = W / 16;
  const int wv = threadIdx.x >> 6, l = threadIdx.x & 63;
  const int lm = l & 15, lg = l >> 4;
  const int total = D * H * NWT;

  // bijective XCD-contiguous block swizzle (gridDim.x must be multiple of 8)
  const unsigned nwg = gridDim.x;
  const unsigned swz = (blockIdx.x & 7u) * (nwg >> 3) + (blockIdx.x >> 3);

  for (int u = (int)swz * 4 + wv; u < total; u += (int)nwg * 4) {
    int rest = u;
    const int wt = rest % NWT; rest /= NWT;
    const int h = rest & (H - 1);
    const int d = rest >> LH;
    f32x4 acc[NT];
    #pragma unroll
    for (int nt = 0; nt < NT; ++nt) acc[nt] = (f32x4){0.f, 0.f, 0.f, 0.f};

    for (int t = 0; t < 27; ++t) {
      const int kd = t / 9, kh = (t / 3) % 3, s = t % 3;
      const int zd = d + kd - 1, zh = h + kh - 1;
      const bool inb = ((unsigned)zd < (unsigned)D) & ((unsigned)zh < (unsigned)H);
      const size_t tile = (((size_t)(s * D + (inb ? zd : 0)) * H + (inb ? zh : 0)) * NWT + wt);
      #pragma unroll
      for (int kc = 0; kc < NKC; ++kc) {
        const unsigned short* src;
        if (kc < NKC1)
          src = inb ? pk1 + (tile * NKC1 + kc) * 512 : ztile;
        else
          src = inb ? pk2 + (tile * (NKC - NKC1) + (kc - NKC1)) * 512 : ztile;
        const short8v a = *(const short8v*)(src + l * 8);
        #pragma unroll
        for (int nt = 0; nt < NT; ++nt) {
          const short8v b = *(const short8v*)(pw + ((((size_t)t * NT + nt) * NKC + kc) << 9) + l * 8);
          acc[nt] = __builtin_amdgcn_mfma_f32_16x16x32_bf16(a, b, acc[nt], 0, 0, 0);
        }
      }
    }

    #pragma unroll
    for (int nt = 0; nt < NT; ++nt) {
      const int co = nt * 16 + lm;
      const float sc = bn[co] * rsqrtf(bn[3 * Co + co] + 1e-5f);
      const float sh = bn[Co + co] - bn[2 * Co + co] * sc;
      #pragma unroll
      for (int i = 0; i < 4; ++i) {
        const int wo = wt * 16 + lg * 4 + i;
        const int v = (((d << LH) + h) << LW) + wo;
        const float y = fmaxf(acc[nt][i] * sc + sh, 0.f) * mask[v];
        out[(size_t)v * Co + co] = f2b(y);
      }
    }
  }
}

// ---------------------------------------------------------------------------
// subm via MFMA (sparse list, full 27 taps): exact R8 body.
// ---------------------------------------------------------------------------
template<int C1p, int C2, int Co, int LW, int LH, int D>
__global__ void __launch_bounds__(TPB) k_subm_m(
    const unsigned short* __restrict__ xb1, const unsigned short* __restrict__ xb2,
    const unsigned short* __restrict__ pw, const float* __restrict__ bn,
    const int* __restrict__ list, const int* __restrict__ cnt,
    const unsigned short* __restrict__ zb, unsigned short* __restrict__ out)
{
  constexpr int NT = Co / 16;
  constexpr int NKC1 = C1p / 32;
  constexpr int NKC = (C1p + C2) / 32;
  constexpr int MH = (NT >= 4) ? 1 : 2;
  constexpr int NTPW = (NT >= 4) ? NT / 4 : 1;
  constexpr int MVB = 32 * MH;
  constexpr int H = 1 << LH, W = 1 << LW;

  const int n = *cnt;
  if (n == 0) return;
  const int nmt = (n + MVB - 1) / MVB;
  const int wv = threadIdx.x >> 6, l = threadIdx.x & 63;
  const int mhalf = (MH == 2) ? (wv >> 1) : 0;
  const int nt0   = (MH == 2) ? (wv & 1) : wv * NTPW;
  const int lm = l & 15, lg = l >> 4;

  for (int mt = blockIdx.x; mt < nmt; mt += gridDim.x) {
    const int r0 = mt * MVB + mhalf * 32;
    int wx[2], hy[2], dzz[2];
    #pragma unroll
    for (int h2 = 0; h2 < 2; ++h2) {
      const int g = min(r0 + h2 * 16 + lm, n - 1);
      const int v = list[g];
      wx[h2] = v & (W - 1); hy[h2] = (v >> LW) & (H - 1); dzz[h2] = v >> (LW + LH);
    }
    f32x4 acc[NTPW][2];
    #pragma unroll
    for (int q = 0; q < NTPW; ++q)
      #pragma unroll
      for (int h2 = 0; h2 < 2; ++h2)
        acc[q][h2] = (f32x4){0.f, 0.f, 0.f, 0.f};

    for (int t = 0; t < 27; ++t) {
      const int kd = t / 9, kh = (t / 3) % 3, kw = t % 3;
      const unsigned short* p1[2];
      const unsigned short* p2[2];
      #pragma unroll
      for (int h2 = 0; h2 < 2; ++h2) {
        const int zd0 = dzz[h2] + kd - 1, zh0 = hy[h2] + kh - 1, zw0 = wx[h2] + kw - 1;
        const bool inb = ((unsigned)zd0 < (unsigned)D) &
                         ((unsigned)zh0 < (unsigned)H) &
                         ((unsigned)zw0 < (unsigned)W);
        const int zd = min(max(zd0, 0), D - 1);
        const int zh = min(max(zh0, 0), H - 1);
        const int zw = min(max(zw0, 0), W - 1);
        const int nv = (((zd << LH) + zh) << LW) + zw;
        p1[h2] = (inb ? xb1 + (size_t)nv * C1p : zb) + lg * 8;
        if constexpr (C2 > 0) p2[h2] = (inb ? xb2 + (size_t)nv * C2 : zb) + lg * 8;
      }
      #pragma unroll
      for (int kc = 0; kc < NKC; ++kc) {
        short8v a0, a1;
        if (C2 == 0 || kc < NKC1) {
          const int coff = kc * 32;
          a0 = *(const short8v*)(p1[0] + coff);
          a1 = *(const short8v*)(p1[1] + coff);
        } else {
          const int coff = (kc - NKC1) * 32;
          a0 = *(const short8v*)(p2[0] + coff);
          a1 = *(const short8v*)(p2[1] + coff);
        }
        #pragma unroll
        for (int q = 0; q < NTPW; ++q) {
          const int nt = nt0 + q;
          const short8v b = *(const short8v*)(pw + ((((size_t)t * NT + nt) * NKC + kc) << 9) + l * 8);
          acc[q][0] = __builtin_amdgcn_mfma_f32_16x16x32_bf16(a0, b, acc[q][0], 0, 0, 0);
          acc[q][1] = __builtin_amdgcn_mfma_f32_16x16x32_bf16(a1, b, acc[q][1], 0, 0, 0);
        }
      }
    }
    #pragma unroll
    for (int q = 0; q < NTPW; ++q) {
      const int nt = nt0 + q;
      const int co = nt * 16 + lm;
      const float sc = bn[co] * rsqrtf(bn[3 * Co + co] + 1e-5f);
      const float sh = bn[Co + co] - bn[2 * Co + co] * sc;
      #pragma unroll
      for (int h2 = 0; h2 < 2; ++h2)
        #pragma unroll
        for (int i = 0; i < 4; ++i) {
          const int g = r0 + h2 * 16 + lg * 4 + i;
          if (g < n) {
            const int v = list[g];
            const float y = fmaxf(acc[q][h2][i] * sc + sh, 0.f);
            out[(size_t)v * Co + co] = f2b(y);
          }
        }
    }
  }
}

// ---------------------------------------------------------------------------
// subm via MFMA, TAP-SPLIT (deep layers): exact R8 body.
// ---------------------------------------------------------------------------
template<int C1p, int C2, int Co, int LW, int LH, int D, int NSPLIT, int CAP>
__global__ void __launch_bounds__(TPB) k_subm_mp(
    const unsigned short* __restrict__ xb1, const unsigned short* __restrict__ xb2,
    const unsigned short* __restrict__ pw,
    const int* __restrict__ list, const int* __restrict__ cnt,
    const unsigned short* __restrict__ zb, float* __restrict__ pbuf)
{
  constexpr int NT = Co / 16;
  constexpr int NKC1 = C1p / 32;
  constexpr int NKC = (C1p + C2) / 32;
  constexpr int MH = (NT >= 4) ? 1 : 2;
  constexpr int NTPW = (NT >= 4) ? NT / 4 : 1;
  constexpr int MVB = 32 * MH;
  constexpr int TPS = 27 / NSPLIT;
  constexpr int H = 1 << LH, W = 1 << LW;

  const int n = *cnt;
  if (n == 0) return;
  const int nmt = (n + MVB - 1) / MVB;
  const int s = blockIdx.y;
  const int wv = threadIdx.x >> 6, l = threadIdx.x & 63;
  const int mhalf = (MH == 2) ? (wv >> 1) : 0;
  const int nt0   = (MH == 2) ? (wv & 1) : wv * NTPW;
  const int lm = l & 15, lg = l >> 4;

  for (int mt = blockIdx.x; mt < nmt; mt += gridDim.x) {
    const int r0 = mt * MVB + mhalf * 32;
    int wx[2], hy[2], dzz[2];
    #pragma unroll
    for (int h2 = 0; h2 < 2; ++h2) {
      const int g = min(r0 + h2 * 16 + lm, n - 1);
      const int v = list[g];
      wx[h2] = v & (W - 1); hy[h2] = (v >> LW) & (H - 1); dzz[h2] = v >> (LW + LH);
    }
    f32x4 acc[NTPW][2];
    #pragma unroll
    for (int q = 0; q < NTPW; ++q)
      #pragma unroll
      for (int h2 = 0; h2 < 2; ++h2)
        acc[q][h2] = (f32x4){0.f, 0.f, 0.f, 0.f};

    for (int t = s * TPS; t < (s + 1) * TPS; ++t) {
      const int kd = t / 9, kh = (t / 3) % 3, kw = t % 3;
      const unsigned short* p1[2];
      const unsigned short* p2[2];
      #pragma unroll
      for (int h2 = 0; h2 < 2; ++h2) {
        const int zd0 = dzz[h2] + kd - 1, zh0 = hy[h2] + kh - 1, zw0 = wx[h2] + kw - 1;
        const bool inb = ((unsigned)zd0 < (unsigned)D) &
                         ((unsigned)zh0 < (unsigned)H) &
                         ((unsigned)zw0 < (unsigned)W);
        const int zd = min(max(zd0, 0), D - 1);
        const int zh = min(max(zh0, 0), H - 1);
        const int zw = min(max(zw0, 0), W - 1);
        const int nv = (((zd << LH) + zh) << LW) + zw;
        p1[h2] = (inb ? xb1 + (size_t)nv * C1p : zb) + lg * 8;
        if constexpr (C2 > 0) p2[h2] = (inb ? xb2 + (size_t)nv * C2 : zb) + lg * 8;
      }
      #pragma unroll
      for (int kc = 0; kc < NKC; ++kc) {
        short8v a0, a1;
        if (C2 == 0 || kc < NKC1) {
          const int coff = kc * 32;
          a0 = *(const short8v*)(p1[0] + coff);
          a1 = *(const short8v*)(p1[1] + coff);
        } else {
          const int coff = (kc - NKC1) * 32;
          a0 = *(const short8v*)(p2[0] + coff);
          a1 = *(const short8v*)(p2[1] + coff);
        }
        #pragma unroll
        for (int q = 0; q < NTPW; ++q) {
          const int nt = nt0 + q;
          const short8v b = *(const short8v*)(pw + ((((size_t)t * NT + nt) * NKC + kc) << 9) + l * 8);
          acc[q][0] = __builtin_amdgcn_mfma_f32_16x16x32_bf16(a0, b, acc[q][0], 0, 0, 0);
          acc[q][1] = __builtin_amdgcn_mfma_f32_16x16x32_bf16(a1, b, acc[q][1], 0, 0, 0);
        }
      }
    }
    #pragma unroll
    for (int q = 0; q < NTPW; ++q) {
      const int co = (nt0 + q) * 16 + lm;
      #pragma unroll
      for (int h2 = 0; h2 < 2; ++h2)
        #pragma unroll
        for (int i = 0; i < 4; ++i) {
          const int g = r0 + h2 * 16 + lg * 4 + i;
          if (g < n)
            pbuf[((size_t)s * CAP + g) * Co + co] = acc[q][h2][i];
        }
    }
  }
}

// sum NSPLIT fp32 partials in fixed order + BN + ReLU -> bf16 out
template<int Co, int NSPLIT, int CAP>
__global__ void __launch_bounds__(TPB) k_reduce_bnb(
    const float* __restrict__ pbuf, const float* __restrict__ bn,
    const int* __restrict__ list, const int* __restrict__ cnt,
    unsigned short* __restrict__ out)
{
  constexpr int TPV = Co / 4;
  const int n = *cnt;
  const int total = n * TPV;
  for (int i = blockIdx.x * TPB + threadIdx.x; i < total; i += gridDim.x * TPB) {
    const int a = i / TPV;
    const int cg = i % TPV;
    float4 acc = make_float4(0.f, 0.f, 0.f, 0.f);
    #pragma unroll
    for (int s = 0; s < NSPLIT; ++s) {
      const float4 p = ld4(pbuf + ((size_t)s * CAP + a) * Co + cg * 4);
      acc.x += p.x; acc.y += p.y; acc.z += p.z; acc.w += p.w;
    }
    const int v = list[a];
    const float4 r = bn_relu4<Co>(acc, bn, cg);
    short4v o; o[0] = (short)f2b(r.x); o[1] = (short)f2b(r.y);
    o[2] = (short)f2b(r.z); o[3] = (short)f2b(r.w);
    *(short4v*)(out + (size_t)v * Co + cg * 4) = o;
  }
}

// ---------------------------------------------------------------------------
// down: 2x2x2 stride-2 conv + BN + ReLU; bf16 acts, fp32 weights/math
// ---------------------------------------------------------------------------
template<int Ci, int Co, int LW, int LH, int D>
__global__ void __launch_bounds__(TPB) k_down_b(
    const unsigned short* __restrict__ x, const float* __restrict__ wgt,
    const float* __restrict__ bn, const float* __restrict__ mfine,
    const int* __restrict__ list, const int* __restrict__ cnt,
    unsigned short* __restrict__ out)
{
  constexpr int TPV = Co / 4;
  constexpr int H = 1 << LH, W = 1 << LW;
  const int n = *cnt;
  const int total = n * TPV;
  for (int i = blockIdx.x * TPB + threadIdx.x; i < total; i += gridDim.x * TPB) {
    const int a = i / TPV;
    const int cg = i % TPV;
    const int v = list[a];
    const int w = v & (W - 1), h = (v >> LW) & (H - 1), d = v >> (LW + LH);
    float4 acc0 = make_float4(0.f, 0.f, 0.f, 0.f);
    float4 acc1 = make_float4(0.f, 0.f, 0.f, 0.f);
    #pragma unroll
    for (int kd = 0; kd < 2; ++kd)
      #pragma unroll
      for (int kh = 0; kh < 2; ++kh)
        #pragma unroll
        for (int kw = 0; kw < 2; ++kw) {
          const int nv = ((((2*d+kd) << (LH+1)) + (2*h+kh)) << (LW+1)) + (2*w+kw);
          if (mfine[nv] == 0.f) continue;
          const int tap = (kd * 2 + kh) * 2 + kw;
          const float4* __restrict__ wp = (const float4*)wgt + (size_t)tap * Ci * TPV + cg;
          const unsigned short* row = x + (size_t)nv * Ci;
          #pragma unroll
          for (int c8 = 0; c8 < Ci / 8; ++c8) {
            const short8v s = *(const short8v*)(row + c8 * 8);
            fma4(b2f((unsigned short)s[0]), wp[(c8 * 8 + 0) * TPV], acc0);
            fma4(b2f((unsigned short)s[1]), wp[(c8 * 8 + 1) * TPV], acc1);
            fma4(b2f((unsigned short)s[2]), wp[(c8 * 8 + 2) * TPV], acc0);
            fma4(b2f((unsigned short)s[3]), wp[(c8 * 8 + 3) * TPV], acc1);
            fma4(b2f((unsigned short)s[4]), wp[(c8 * 8 + 4) * TPV], acc0);
            fma4(b2f((unsigned short)s[5]), wp[(c8 * 8 + 5) * TPV], acc1);
            fma4(b2f((unsigned short)s[6]), wp[(c8 * 8 + 6) * TPV], acc0);
            fma4(b2f((unsigned short)s[7]), wp[(c8 * 8 + 7) * TPV], acc1);
          }
        }
    float4 acc;
    acc.x = acc0.x + acc1.x; acc.y = acc0.y + acc1.y;
    acc.z = acc0.z + acc1.z; acc.w = acc0.w + acc1.w;
    const float4 r = bn_relu4<Co>(acc, bn, cg);
    short4v o; o[0] = (short)f2b(r.x); o[1] = (short)f2b(r.y);
    o[2] = (short)f2b(r.z); o[3] = (short)f2b(r.w);
    *(short4v*)(out + (size_t)v * Co + cg * 4) = o;
  }
}

// ---------------------------------------------------------------------------
// up: 1-tap conv_transpose; bf16 acts, fp32 weights/math
// ---------------------------------------------------------------------------
template<int Ci, int Co, int LW, int LH>
__global__ void __launch_bounds__(TPB) k_up_b(
    const unsigned short* __restrict__ x, const float* __restrict__ wgt,
    const int* __restrict__ list, const int* __restrict__ cnt,
    unsigned short* __restrict__ out)
{
  constexpr int TPV = Co / 4;
  constexpr int H = 1 << LH, W = 1 << LW;
  const int n = *cnt;
  const int total = n * TPV;
  for (int i = blockIdx.x * TPB + threadIdx.x; i < total; i += gridDim.x * TPB) {
    const int a = i / TPV;
    const int cg = i % TPV;
    const int v = list[a];
    const int w = v & (W - 1), h = (v >> LW) & (H - 1), d = v >> (LW + LH);
    const int kd = 1 - (d & 1), kh = 1 - (h & 1), kw = 1 - (w & 1);
    const int nv = ((((d >> 1) << (LH - 1)) + (h >> 1)) << (LW - 1)) + (w >> 1);
    const int tap = (kd * 2 + kh) * 2 + kw;
    const float4* __restrict__ wp = (const float4*)wgt + (size_t)tap * Ci * TPV + cg;
    const unsigned short* row = x + (size_t)nv * Ci;
    float4 acc0 = make_float4(0.f, 0.f, 0.f, 0.f);
    float4 acc1 = make_float4(0.f, 0.f, 0.f, 0.f);
    #pragma unroll
    for (int c8 = 0; c8 < Ci / 8; ++c8) {
      const short8v s = *(const short8v*)(row + c8 * 8);
      fma4(b2f((unsigned short)s[0]), wp[(c8 * 8 + 0) * TPV], acc0);
      fma4(b2f((unsigned short)s[1]), wp[(c8 * 8 + 1) * TPV], acc1);
      fma4(b2f((unsigned short)s[2]), wp[(c8 * 8 + 2) * TPV], acc0);
      fma4(b2f((unsigned short)s[3]), wp[(c8 * 8 + 3) * TPV], acc1);
      fma4(b2f((unsigned short)s[4]), wp[(c8 * 8 + 4) * TPV], acc0);
      fma4(b2f((unsigned short)s[5]), wp[(c8 * 8 + 5) * TPV], acc1);
      fma4(b2f((unsigned short)s[6]), wp[(c8 * 8 + 6) * TPV], acc0);
      fma4(b2f((unsigned short)s[7]), wp[(c8 * 8 + 7) * TPV], acc1);
    }
    short4v o;
    o[0] = (short)f2b(acc0.x + acc1.x); o[1] = (short)f2b(acc0.y + acc1.y);
    o[2] = (short)f2b(acc0.z + acc1.z); o[3] = (short)f2b(acc0.w + acc1.w);
    *(short4v*)(out + (size_t)v * Co + cg * 4) = o;
  }
}

// ---------------------------------------------------------------------------
// head: bf16 c0, fp32 weights; scatter into 5 output regions
// ---------------------------------------------------------------------------
__global__ void __launch_bounds__(TPB) k_head_b(
    const unsigned short* __restrict__ c0, const float* __restrict__ wh,
    const float* __restrict__ bh, const int* __restrict__ list,
    const int* __restrict__ cnt, float* __restrict__ out)
{
  __shared__ float sw[32 * 45];
  __shared__ float sb[45];
  for (int t = threadIdx.x; t < 32 * 45; t += TPB) sw[t] = wh[t];
  if (threadIdx.x < 45) sb[threadIdx.x] = bh[threadIdx.x];
  __syncthreads();
  const int n = *cnt;
  const int total = n * 45;
  const size_t NV = 524288;
  for (int i = blockIdx.x * TPB + threadIdx.x; i < total; i += gridDim.x * TPB) {
    const int a = i / 45;
    const int j = i % 45;
    const int v = list[a];
    const unsigned short* cp = c0 + (size_t)v * 32;
    float a0 = 0.f, a1 = 0.f;
    #pragma unroll
    for (int c8 = 0; c8 < 4; ++c8) {
      const short8v s = *(const short8v*)(cp + c8 * 8);
      a0 = fmaf(b2f((unsigned short)s[0]), sw[(c8 * 8 + 0) * 45 + j], a0);
      a1 = fmaf(b2f((unsigned short)s[1]), sw[(c8 * 8 + 1) * 45 + j], a1);
      a0 = fmaf(b2f((unsigned short)s[2]), sw[(c8 * 8 + 2) * 45 + j], a0);
      a1 = fmaf(b2f((unsigned short)s[3]), sw[(c8 * 8 + 3) * 45 + j], a1);
      a0 = fmaf(b2f((unsigned short)s[4]), sw[(c8 * 8 + 4) * 45 + j], a0);
      a1 = fmaf(b2f((unsigned short)s[5]), sw[(c8 * 8 + 5) * 45 + j], a1);
      a0 = fmaf(b2f((unsigned short)s[6]), sw[(c8 * 8 + 6) * 45 + j], a0);
      a1 = fmaf(b2f((unsigned short)s[7]), sw[(c8 * 8 + 7) * 45 + j], a1);
    }
    const float val = a0 + a1 + sb[j];
    const int k = j / 9, r = j % 9;
    if (r < 3)
      out[(size_t)v * 15 + k * 3 + r] = val;
    else if (r < 6)
      out[NV * 15 + (size_t)v * 15 + k * 3 + (r - 3)] = fminf(fmaxf(val, -5.f), 3.f);
    else if (r == 6)
      out[NV * 30 + (size_t)v * 5 + k] = val;
    else if (r == 7)
      out[NV * 35 + (size_t)v * 5 + k] = val;
    else
      out[NV * 40 + (size_t)v * 5 + k] = val;
  }
}

// ---------------------------------------------------------------------------
extern "C" void kernel_launch(void* const* d_in, const int* in_sizes, int n_in,
                              void* d_out, int out_size, void* d_ws, size_t ws_size,
                              hipStream_t stream)
{
  (void)in_sizes; (void)n_in;

  const float* x        = (const float*)d_in[0];
  const float* mask0    = (const float*)d_in[1];
  const float* w_enc0   = (const float*)d_in[2];
  const float* bn_enc0  = (const float*)d_in[3];
  const float* w_down0  = (const float*)d_in[4];
  const float* bn_down0 = (const float*)d_in[5];
  const float* w_enc1   = (const float*)d_in[6];
  const float* bn_enc1  = (const float*)d_in[7];
  const float* w_down1  = (const float*)d_in[8];
  const float* bn_down1 = (const float*)d_in[9];
  const float* w_enc2   = (const float*)d_in[10];
  const float* bn_enc2  = (const float*)d_in[11];
  const float* w_down2  = (const float*)d_in[12];
  const float* bn_down2 = (const float*)d_in[13];
  const float* w_bott   = (const float*)d_in[14];
  const float* bn_bott  = (const float*)d_in[15];
  const float* w_up2    = (const float*)d_in[16];
  const float* w_dec2   = (const float*)d_in[17];
  const float* bn_dec2  = (const float*)d_in[18];
  const float* w_up1    = (const float*)d_in[19];
  const float* w_dec1   = (const float*)d_in[20];
  const float* bn_dec1  = (const float*)d_in[21];
  const float* w_up0    = (const float*)d_in[22];
  const float* w_dec0   = (const float*)d_in[23];
  const float* bn_dec0  = (const float*)d_in[24];
  const float* w_head   = (const float*)d_in[25];
  const float* b_head   = (const float*)d_in[26];

  char* ws = (char*)d_ws;
  size_t o = 0;
  auto takeB = [&](size_t bytes) { char* p = ws + o; o += (bytes + 255) & ~(size_t)255; return p; };
  auto takeU = [&](size_t elems) { return (unsigned short*)takeB(elems * 2); };
  auto takeF = [&](size_t elems) { return (float*)takeB(elems * 4); };
  auto takeI = [&](size_t elems) { return (int*)takeB(elems * 4); };

  int*   cnt   = takeI(16);
  int*   bcnt  = takeI(2048);
  int*   boff  = takeI(2048);
  int*   list0 = takeI(524288);
  int*   list1 = takeI(65536);
  int*   list2 = takeI(8192);
  int*   list3 = takeI(1024);
  float* m1    = takeF(65536);
  float* m2    = takeF(8192);
  float* m3    = takeF(1024);
  unsigned short* zb    = takeU(256);
  unsigned short* ztile = takeU(512);
  float* pbuf = takeF(3145728);            // K-split partials (deep layers)
  // packed weights (bf16)
  unsigned short* pw_enc0 = takeU(27648);
  unsigned short* pw_enc1 = takeU(110592);
  unsigned short* pw_enc2 = takeU(442368);
  unsigned short* pw_bott = takeU(1769472);
  unsigned short* pw_dec2 = takeU(884736);
  unsigned short* pw_dec1 = takeU(221184);
  unsigned short* pw_dec0 = takeU(55296);
  // packed-A region for L1 dense layers (enc1 aliases dec1's first half)
  unsigned short* pkbuf = takeU(25165824);
  unsigned short* pk1 = pkbuf;             // enc1 (12.58M)
  unsigned short* pke = pkbuf;             // dec1 skip  (12.58M)
  unsigned short* pku = pkbuf + 12582912;  // dec1 up    (12.58M)
  // bf16 activations
  unsigned short* xb  = takeU(16777216);
  unsigned short* e0b = takeU(16777216);
  unsigned short* d0b = takeU(4194304);    // reused as u1b
  unsigned short* e1b = takeU(4194304);
  unsigned short* d1b = takeU(1048576);    // reused as u2b
  unsigned short* e2b = takeU(1048576);
  unsigned short* d2b = takeU(262144);
  unsigned short* bbb = takeU(262144);
  unsigned short* c2b = takeU(1048576);
  unsigned short* c1b = takeU(4194304);
  unsigned short* u0b = takeU(16777216);
  unsigned short* c0b = takeU(16777216);
  if (o > ws_size) return;
  unsigned short* u1b = d0b;
  unsigned short* u2b = d1b;
  int* cnt0 = cnt, *cnt1 = cnt + 1, *cnt2 = cnt + 2, *cnt3 = cnt + 3;

  hipMemsetAsync(d_out, 0, (size_t)out_size * sizeof(float), stream);
  hipMemsetAsync(zb, 0, 256 * 2, stream);
  hipMemsetAsync(ztile, 0, 512 * 2, stream);
  hipMemsetAsync(e0b, 0, 16777216ull * 2, stream);
  hipMemsetAsync(d0b, 0, 4194304ull * 2, stream);
  hipMemsetAsync(d1b, 0, 1048576ull * 2, stream);
  hipMemsetAsync(e2b, 0, 1048576ull * 2, stream);
  hipMemsetAsync(d2b, 0, 262144ull * 2, stream);
  hipMemsetAsync(u0b, 0, 16777216ull * 2, stream);

  auto g = [](long long upper) {
    unsigned b = (unsigned)((upper + TPB - 1) / TPB);
    return dim3(b > 4096u ? 4096u : (b ? b : 1u));
  };

  // weight packs + x convert
  k_packw<20, 32, 0, 32><<<g(27648), TPB, 0, stream>>>(w_enc0, pw_enc0);
  k_packw<64, 64, 0, 64><<<g(110592), TPB, 0, stream>>>(w_enc1, pw_enc1);
  k_packw<128, 128, 0, 128><<<g(442368), TPB, 0, stream>>>(w_enc2, pw_enc2);
  k_packw<256, 256, 0, 256><<<g(1769472), TPB, 0, stream>>>(w_bott, pw_bott);
  k_packw<128, 128, 128, 128><<<g(884736), TPB, 0, stream>>>(w_dec2, pw_dec2);
  k_packw<64, 64, 64, 64><<<g(221184), TPB, 0, stream>>>(w_dec1, pw_dec1);
  k_packw<32, 32, 32, 32><<<g(55296), TPB, 0, stream>>>(w_dec0, pw_dec0);
  k_cvtx<<<dim3(524288 / TPB), TPB, 0, stream>>>(x, xb, 524288);

  // mask pyramid + ordered compaction
  k_maskpool<6, 6, 16><<<g(65536), TPB, 0, stream>>>(mask0, m1);
  k_maskpool<5, 5, 8><<<g(8192), TPB, 0, stream>>>(m1, m2);
  k_maskpool<4, 4, 4><<<g(1024), TPB, 0, stream>>>(m2, m3);
  auto compact = [&](const float* m, int total, int* list, int* cptr) {
    const int nb = total / TPB;
    k_count<<<dim3((unsigned)nb), TPB, 0, stream>>>(m, total, bcnt);
    k_scan<<<dim3(1), 1024, 0, stream>>>(bcnt, nb, boff, cptr);
    k_fill<<<dim3((unsigned)nb), TPB, 0, stream>>>(m, total, boff, list);
  };
  compact(mask0, 524288, list0, cnt0);
  compact(m1,     65536, list1, cnt1);
  compact(m2,      8192, list2, cnt2);
  compact(m3,      1024, list3, cnt3);

  // encoder
  k_subm_m<32, 0, 32, 7, 7, 32><<<dim3(2048), TPB, 0, stream>>>(xb, nullptr, pw_enc0, bn_enc0, list0, cnt0, zb, e0b);
  k_down_b<32, 64, 6, 6, 16><<<g(65536LL * 16), TPB, 0, stream>>>(e0b, w_down0, bn_down0, mask0, list1, cnt1, d0b);
  // enc1: pack + dense conv (A shared across all 4 co-tiles, XCD swizzle)
  k_packa<64, 6, 6, 16><<<dim3(6144), TPB, 0, stream>>>(d0b, pk1);
  k_subm_dp<64, 6, 6, 16, 2, 2><<<dim3(1024), TPB, 0, stream>>>(pk1, nullptr, pw_enc1, bn_enc1, m1, ztile, e1b);
  k_down_b<64, 128, 5, 5, 8><<<g(8192LL * 32), TPB, 0, stream>>>(e1b, w_down1, bn_down1, m1, list2, cnt2, d1b);
  // enc2: tap-split x3
  k_subm_mp<128, 0, 128, 5, 5, 8, 3, 8192><<<dim3(256, 3), TPB, 0, stream>>>(d1b, nullptr, pw_enc2, list2, cnt2, zb, pbuf);
  k_reduce_bnb<128, 3, 8192><<<g(8192LL * 32), TPB, 0, stream>>>(pbuf, bn_enc2, list2, cnt2, e2b);
  k_down_b<128, 256, 4, 4, 4><<<g(1024LL * 64), TPB, 0, stream>>>(e2b, w_down2, bn_down2, m2, list3, cnt3, d2b);
  // bottleneck: tap-split x9
  k_subm_mp<256, 0, 256, 4, 4, 4, 9, 1024><<<dim3(32, 9), TPB, 0, stream>>>(d2b, nullptr, pw_bott, list3, cnt3, zb, pbuf);
  k_reduce_bnb<256, 9, 1024><<<g(1024LL * 64), TPB, 0, stream>>>(pbuf, bn_bott, list3, cnt3, bbb);
  // decoder
  k_up_b<256, 128, 5, 5><<<g(8192LL * 32), TPB, 0, stream>>>(bbb, w_up2, list2, cnt2, u2b);
  // dec2: tap-split x3 (concat u2|e2)
  k_subm_mp<128, 128, 128, 5, 5, 8, 3, 8192><<<dim3(256, 3), TPB, 0, stream>>>(u2b, e2b, pw_dec2, list2, cnt2, zb, pbuf);
  k_reduce_bnb<128, 3, 8192><<<g(8192LL * 32), TPB, 0, stream>>>(pbuf, bn_dec2, list2, cnt2, c2b);
  k_up_b<128, 64, 6, 6><<<g(65536LL * 16), TPB, 0, stream>>>(c2b, w_up1, list1, cnt1, u1b);
  // dec1: pack u1b+e1b, dense conv (concat u1|e1, A shared, XCD swizzle)
  k_packa<64, 6, 6, 16><<<dim3(6144), TPB, 0, stream>>>(u1b, pku);
  k_packa<64, 6, 6, 16><<<dim3(6144), TPB, 0, stream>>>(e1b, pke);
  k_subm_dp<64, 6, 6, 16, 2, 4><<<dim3(1024), TPB, 0, stream>>>(pku, pke, pw_dec1, bn_dec1, m1, ztile, c1b);
  k_up_b<64, 32, 7, 7><<<g(524288LL * 8), TPB, 0, stream>>>(c1b, w_up0, list0, cnt0, u0b);
  k_subm_m<32, 32, 32, 7, 7, 32><<<dim3(2048), TPB, 0, stream>>>(u0b, e0b, pw_dec0, bn_dec0, list0, cnt0, zb, c0b);
  // head
  k_head_b<<<g(524288LL * 45), TPB, 0, stream>>>(c0b, w_head, b_head, list0, cnt0, (float*)d_out);
}